// Round 1
// baseline (9032.853 us; speedup 1.0000x reference)
//
#include <hip/hip_runtime.h>
#include <hip/hip_bf16.h>
#include <math.h>

#define S 2048
#define NH 16
#define DIM 2048
#define QK_NOPE 128
#define QK_ROPE 64
#define QK_HD 192
#define V_HD 128
#define Q_LORA 1536
#define KV_LORA 512
#define IDX_HD 128

typedef __hip_bfloat16 bf16;

// ---------------- generic f32 GEMM: C[M,N] = alpha * A[M,K] @ B[N,K]^T ----------------
// M multiple of 64; K multiple of 16; N arbitrary (guarded).
__global__ __launch_bounds__(256) void gemm_nt(const float* __restrict__ A,
                                               const float* __restrict__ B,
                                               float* __restrict__ C,
                                               int M, int N, int K, float alpha) {
    __shared__ float As[64][17];
    __shared__ float Bs[64][17];
    const int bm = blockIdx.y * 64, bn = blockIdx.x * 64;
    const int tid = threadIdx.x;
    const int tr = (tid >> 4) << 2, tc = (tid & 15) << 2;
    float acc[4][4] = {};
    for (int k0 = 0; k0 < K; k0 += 16) {
        for (int u = 0; u < 4; ++u) {
            int idx = tid + u * 256;
            int rr = idx >> 4, cc = idx & 15;
            As[rr][cc] = A[(size_t)(bm + rr) * K + k0 + cc];
            Bs[rr][cc] = (bn + rr < N) ? B[(size_t)(bn + rr) * K + k0 + cc] : 0.f;
        }
        __syncthreads();
        for (int kk = 0; kk < 16; ++kk) {
            float a[4], b[4];
            for (int i = 0; i < 4; ++i) a[i] = As[tr + i][kk];
            for (int j = 0; j < 4; ++j) b[j] = Bs[tc + j][kk];
            for (int i = 0; i < 4; ++i)
                for (int j = 0; j < 4; ++j) acc[i][j] += a[i] * b[j];
        }
        __syncthreads();
    }
    for (int i = 0; i < 4; ++i)
        for (int j = 0; j < 4; ++j)
            if (bn + tc + j < N)
                C[(size_t)(bm + tr + i) * N + bn + tc + j] = alpha * acc[i][j];
}

// ---------------- RMSNorm: one block per row ----------------
__global__ __launch_bounds__(256) void rms_kernel(const float* __restrict__ in, float* __restrict__ out,
                                                  const float* __restrict__ w, int C, int ldin, int ldout) {
    const int row = blockIdx.x;
    const float* xr = in + (size_t)row * ldin;
    float* yr = out + (size_t)row * ldout;
    float ss = 0.f;
    for (int c = threadIdx.x; c < C; c += 256) { float v = xr[c]; ss += v * v; }
    for (int o = 32; o; o >>= 1) ss += __shfl_down(ss, o, 64);
    __shared__ float red[4];
    const int wave = threadIdx.x >> 6, lane = threadIdx.x & 63;
    if (lane == 0) red[wave] = ss;
    __syncthreads();
    const float tot = red[0] + red[1] + red[2] + red[3];
    const float scale = rsqrtf(tot / (float)C + 1e-6f);
    for (int c = threadIdx.x; c < C; c += 256) yr[c] = w[c] * (xr[c] * scale);
}

// ---------------- LayerNorm for ik: row length 128, block of 128 ----------------
__global__ __launch_bounds__(128) void ln_kernel(float* __restrict__ x, const float* __restrict__ w,
                                                 const float* __restrict__ b) {
    const int row = blockIdx.x;
    float* xr = x + (size_t)row * 128;
    const int tid = threadIdx.x;
    float v = xr[tid];
    float sm = v;
    for (int o = 32; o; o >>= 1) sm += __shfl_down(sm, o, 64);
    __shared__ float red[2];
    if ((tid & 63) == 0) red[tid >> 6] = sm;
    __syncthreads();
    const float mu = (red[0] + red[1]) * (1.f / 128.f);
    __syncthreads();
    float d = v - mu;
    float sv = d * d;
    for (int o = 32; o; o >>= 1) sv += __shfl_down(sv, o, 64);
    if ((tid & 63) == 0) red[tid >> 6] = sv;
    __syncthreads();
    const float var = (red[0] + red[1]) * (1.f / 128.f);
    const float rs = rsqrtf(var + 1e-6f);
    xr[tid] = (v - mu) * rs * w[tid] + b[tid];
}

// ---------------- RoPE interleaved (pairs 2k,2k+1) on dims [off, off+64) ----------------
__global__ __launch_bounds__(256) void rope_inter_kernel(float* __restrict__ X, const float* __restrict__ ct,
                                                         const float* __restrict__ st, int H, int hs, int off) {
    int idx = blockIdx.x * 256 + threadIdx.x;
    int k = idx & 31;
    int h = (idx >> 5) % H;
    int s = idx / (32 * H);
    if (s >= S) return;
    float c = ct[s * 32 + k], sn = st[s * 32 + k];
    float* p = X + ((size_t)s * H + h) * hs + off;
    float x1 = p[2 * k], x2 = p[2 * k + 1];
    p[2 * k]     = x1 * c - x2 * sn;
    p[2 * k + 1] = x1 * sn + x2 * c;
}

// ---------------- RoPE half (x1=dims[0:32], x2=dims[32:64]) on first 64 dims of each head ----------------
__global__ __launch_bounds__(256) void rope_half_kernel(float* __restrict__ X, const float* __restrict__ ct,
                                                        const float* __restrict__ st, int H, int hs) {
    int idx = blockIdx.x * 256 + threadIdx.x;
    int k = idx & 31;
    int h = (idx >> 5) % H;
    int s = idx / (32 * H);
    if (s >= S) return;
    float c = ct[s * 32 + k], sn = st[s * 32 + k];
    float* p = X + ((size_t)s * H + h) * hs;
    float x1 = p[k], x2 = p[32 + k];
    p[k]      = x1 * c - x2 * sn;
    p[32 + k] = x1 * sn + x2 * c;
}

// ---------------- Hadamard rotate: y = bf16( bf16(sum_d bf16(x_d)*H[d][j]) * 128^-0.5 ) ----------------
__global__ __launch_bounds__(128) void rotate_kernel(const float* __restrict__ in, bf16* __restrict__ out) {
    __shared__ float xs[128];
    const int r = blockIdx.x, j = threadIdx.x;
    float v = in[(size_t)r * 128 + j];
    xs[j] = __bfloat162float(__float2bfloat16(v));
    __syncthreads();
    float acc = 0.f;
    for (int d = 0; d < 128; ++d) {
        float xv = xs[d];
        acc += (__popc(d & j) & 1) ? -xv : xv;
    }
    float t = __bfloat162float(__float2bfloat16(acc)) * 0.08838834764831845f;
    out[(size_t)r * 128 + j] = __float2bfloat16(t);
}

// ---------------- wq = bf16( (iw[s,h] * f32(iq_rot)) * 128^-0.5 ), in place over iq_rot ----------------
__global__ __launch_bounds__(256) void wq_kernel(const float* __restrict__ iw, bf16* __restrict__ iqr) {
    int idx = blockIdx.x * 256 + threadIdx.x;
    int sh = idx >> 7;
    float a = iw[sh];
    float v = __bfloat162float(iqr[idx]);
    float t = (a * v) * 0.08838834764831845f;
    iqr[idx] = __float2bfloat16(t);
}

// ---------------- index score: out[s,t] = sum_h relu( sum_d wq[s,h,d]*ik[t,d] ) ----------------
__global__ __launch_bounds__(256) void iscore_kernel(const bf16* __restrict__ wq, const bf16* __restrict__ ik,
                                                     float* __restrict__ out) {
    const int bt = blockIdx.x * 64, bs = blockIdx.y * 64;
    if (bs + 63 < bt) return;  // entire tile strictly above diagonal: never read
    __shared__ float As[64][17];
    __shared__ float Bs[64][17];
    const int tid = threadIdx.x;
    const int tr = (tid >> 4) << 2, tc = (tid & 15) << 2;
    float acc[4][4] = {};
    for (int h = 0; h < 16; ++h) {
        float acch[4][4] = {};
        for (int k0 = 0; k0 < 128; k0 += 16) {
            for (int u = 0; u < 4; ++u) {
                int idx = tid + u * 256;
                int rr = idx >> 4, cc = idx & 15;
                As[rr][cc] = __bfloat162float(wq[(size_t)(bs + rr) * 2048 + h * 128 + k0 + cc]);
                Bs[rr][cc] = __bfloat162float(ik[(size_t)(bt + rr) * 128 + k0 + cc]);
            }
            __syncthreads();
            for (int kk = 0; kk < 16; ++kk) {
                float a[4], b[4];
                for (int i = 0; i < 4; ++i) a[i] = As[tr + i][kk];
                for (int j = 0; j < 4; ++j) b[j] = Bs[tc + j][kk];
                for (int i = 0; i < 4; ++i)
                    for (int j = 0; j < 4; ++j) acch[i][j] += a[i] * b[j];
            }
            __syncthreads();
        }
        for (int i = 0; i < 4; ++i)
            for (int j = 0; j < 4; ++j) acc[i][j] += fmaxf(acch[i][j], 0.f);
    }
    for (int i = 0; i < 4; ++i)
        for (int j = 0; j < 4; ++j)
            out[(size_t)(bs + tr + i) * 2048 + bt + tc + j] = acc[i][j];
}

// ---------------- top-k: per row, bitonic sort 2048 (val<<32 | 2048-t) keys descending ----------------
__global__ __launch_bounds__(256) void topk_kernel(const float* __restrict__ isc, int* __restrict__ tk) {
    __shared__ unsigned long long keys[2048];
    const int s = blockIdx.x;
    const float* row = isc + (size_t)s * 2048;
    for (int t = threadIdx.x; t < 2048; t += 256) {
        unsigned long long kk = 0ull;
        if (t <= s) {
            unsigned int vb = __float_as_uint(row[t]);  // relu-sums >= 0: uint order == float order
            kk = ((unsigned long long)vb << 32) | (unsigned int)(2048 - t);
        }
        keys[t] = kk;
    }
    __syncthreads();
    for (int k = 2; k <= 2048; k <<= 1) {
        for (int j = k >> 1; j > 0; j >>= 1) {
            for (int t = threadIdx.x; t < 2048; t += 256) {
                int l = t ^ j;
                if (l > t) {
                    bool up = ((t & k) == 0);
                    unsigned long long a = keys[t], b = keys[l];
                    bool sw = up ? (a < b) : (a > b);
                    if (sw) { keys[t] = b; keys[l] = a; }
                }
            }
            __syncthreads();
        }
    }
    const int cnt = min(1024, s + 1);
    for (int i = threadIdx.x; i < 1024; i += 256) {
        int t = (i < cnt) ? (2048 - (int)(keys[i] & 0xFFFFFFFFull)) : -1;
        tk[(size_t)s * 1024 + i] = t;
    }
}

// ---------------- fused attention per (s, h): q_abs, gathered scores, softmax, PV, out-proj ----------------
__global__ __launch_bounds__(256) void attn_kernel(const float* __restrict__ q, const float* __restrict__ kv,
                                                   const float* __restrict__ kvp, const float* __restrict__ kv_b,
                                                   const int* __restrict__ topk, float* __restrict__ o2) {
    const int s = blockIdx.x, h = blockIdx.y;
    const int tid = threadIdx.x;
    const int wave = tid >> 6, lane = tid & 63;
    __shared__ float qn[128], qpe[64], qabs[512], sc[1024], o1[512], red[4];
    __shared__ int tks[1024];
    const float* qrow = q + ((size_t)s * NH + h) * QK_HD;
    if (tid < 128) qn[tid] = qrow[tid];
    else if (tid < 192) qpe[tid - 128] = qrow[tid];
    const int cnt = min(1024, s + 1);
    for (int j = tid; j < cnt; j += 256) tks[j] = topk[(size_t)s * 1024 + j];
    __syncthreads();
    // q_abs[c] = sum_d qn[d] * wkv1[h,d,c]
    for (int c = tid; c < 512; c += 256) {
        float a = 0.f;
        const float* wp = kv_b + (size_t)(h * 256) * 512 + c;
        for (int d = 0; d < 128; ++d) a += qn[d] * wp[(size_t)d * 512];
        qabs[c] = a;
    }
    __syncthreads();
    // scores: one wave per gathered key
    for (int j = wave; j < cnt; j += 4) {
        int t = tks[j];
        const float* kvr = kv + (size_t)t * 512;
        float a = 0.f;
        for (int c = lane; c < 512; c += 64) a += qabs[c] * kvr[c];
        a += qpe[lane] * kvp[(size_t)t * 576 + 512 + lane];
        for (int o = 32; o; o >>= 1) a += __shfl_down(a, o, 64);
        if (lane == 0) sc[j] = a * 0.07216878364870323f;
    }
    for (int j = cnt + tid; j < 1024; j += 256) sc[j] = -INFINITY;
    __syncthreads();
    // softmax
    float lm = -INFINITY;
    for (int j = tid; j < 1024; j += 256) lm = fmaxf(lm, sc[j]);
    for (int o = 32; o; o >>= 1) lm = fmaxf(lm, __shfl_down(lm, o, 64));
    if (lane == 0) red[wave] = lm;
    __syncthreads();
    const float m = fmaxf(fmaxf(red[0], red[1]), fmaxf(red[2], red[3]));
    __syncthreads();
    float ls = 0.f;
    for (int j = tid; j < 1024; j += 256) { float e = __expf(sc[j] - m); sc[j] = e; ls += e; }
    for (int o = 32; o; o >>= 1) ls += __shfl_down(ls, o, 64);
    if (lane == 0) red[wave] = ls;
    __syncthreads();
    const float inv = 1.f / (red[0] + red[1] + red[2] + red[3]);
    // PV: thread owns 2 consecutive cols of the 512-wide kv
    float2 a2 = make_float2(0.f, 0.f);
    for (int j = 0; j < cnt; ++j) {
        const float2* kvr = (const float2*)(kv + (size_t)tks[j] * 512);
        float p = sc[j];
        float2 v = kvr[tid];
        a2.x += p * v.x;
        a2.y += p * v.y;
    }
    o1[2 * tid]     = a2.x * inv;
    o1[2 * tid + 1] = a2.y * inv;
    __syncthreads();
    // out-proj: o2[s, h*128+d] = sum_c o1[c] * wkv2[h,d,c]; two threads per d
    const int d = tid >> 1, half = tid & 1;
    const float* wp2 = kv_b + (size_t)(h * 256 + 128 + d) * 512 + half * 256;
    float a = 0.f;
    for (int c = 0; c < 256; ++c) a += o1[half * 256 + c] * wp2[c];
    a += __shfl_down(a, 1, 64);
    if (half == 0) o2[(size_t)s * 2048 + h * 128 + d] = a;
}

extern "C" void kernel_launch(void* const* d_in, const int* in_sizes, int n_in,
                              void* d_out, int out_size, void* d_ws, size_t ws_size,
                              hipStream_t stream) {
    const float* x         = (const float*)d_in[0];
    const float* fcos      = (const float*)d_in[2];
    const float* fsin      = (const float*)d_in[3];
    const float* q_a_proj  = (const float*)d_in[5];
    const float* q_a_ln_w  = (const float*)d_in[6];
    const float* q_b_proj  = (const float*)d_in[7];
    const float* kv_a_proj = (const float*)d_in[8];
    const float* kv_a_ln_w = (const float*)d_in[9];
    const float* kv_b      = (const float*)d_in[10];
    const float* o_proj    = (const float*)d_in[11];
    const float* idx_wq_b  = (const float*)d_in[12];
    const float* idx_wk    = (const float*)d_in[13];
    const float* iknw      = (const float*)d_in[14];
    const float* iknb      = (const float*)d_in[15];
    const float* idx_wp    = (const float*)d_in[16];
    float* out = (float*)d_out;

    char* ws = (char*)d_ws;
    size_t off = 0;
    auto alloc = [&](size_t bytes) {
        char* p = ws + off;
        off += (bytes + 255) & ~(size_t)255;
        return p;
    };
    float* qr  = (float*)alloc((size_t)S * Q_LORA * 4);       // 12.6 MB
    float* q   = (float*)alloc((size_t)S * NH * QK_HD * 4);   // 25.2 MB
    float* kvp = (float*)alloc((size_t)S * 576 * 4);          // 4.7 MB
    float* kv  = (float*)alloc((size_t)S * KV_LORA * 4);      // 4.2 MB
    // R1 region: iqf (f32 iq) -> iscore -> o2 (lifetimes disjoint, stream-ordered)
    float* R1  = (float*)alloc((size_t)S * 2048 * 4);         // 16.8 MB
    float* iqf = R1;
    float* isc = R1;
    float* o2  = R1;
    float* ikf = (float*)alloc((size_t)S * 128 * 4);          // 1.0 MB
    float* iw  = (float*)alloc((size_t)S * 16 * 4);           // 0.13 MB
    bf16* iqr  = (bf16*)alloc((size_t)S * 2048 * 2);          // 8.4 MB (becomes wq in place)
    bf16* ikr  = (bf16*)alloc((size_t)S * 128 * 2);           // 0.5 MB
    int* tk    = (int*)alloc((size_t)S * 1024 * 4);           // 8.4 MB

    // qr = rms(x @ q_a_proj.T) * w
    gemm_nt<<<dim3(Q_LORA / 64, S / 64), 256, 0, stream>>>(x, q_a_proj, qr, S, Q_LORA, DIM, 1.f);
    rms_kernel<<<S, 256, 0, stream>>>(qr, qr, q_a_ln_w, Q_LORA, Q_LORA, Q_LORA);
    // q = qr @ q_b_proj.T  (then rope on pe part)
    gemm_nt<<<dim3(NH * QK_HD / 64, S / 64), 256, 0, stream>>>(qr, q_b_proj, q, S, NH * QK_HD, Q_LORA, 1.f);
    // kvp = x @ kv_a_proj.T ; kv = rms(kvp[:, :512]) ; k_pe = rope(kvp[:, 512:])
    gemm_nt<<<dim3(576 / 64, S / 64), 256, 0, stream>>>(x, kv_a_proj, kvp, S, 576, DIM, 1.f);
    rms_kernel<<<S, 256, 0, stream>>>(kvp, kv, kv_a_ln_w, KV_LORA, 576, KV_LORA);
    rope_inter_kernel<<<S * NH * 32 / 256, 256, 0, stream>>>(q, fcos, fsin, NH, QK_HD, QK_NOPE);
    rope_inter_kernel<<<S * 32 / 256, 256, 0, stream>>>(kvp, fcos, fsin, 1, 576, KV_LORA);
    // indexer: iq = qr @ idx_wq_b.T -> rope_half -> rotate
    gemm_nt<<<dim3(2048 / 64, S / 64), 256, 0, stream>>>(qr, idx_wq_b, iqf, S, 2048, Q_LORA, 1.f);
    rope_half_kernel<<<S * NH * 32 / 256, 256, 0, stream>>>(iqf, fcos, fsin, NH, 128);
    // ik = LN(x @ idx_wk.T) -> rope_half -> rotate
    gemm_nt<<<dim3(2, S / 64), 256, 0, stream>>>(x, idx_wk, ikf, S, 128, DIM, 1.f);
    ln_kernel<<<S, 128, 0, stream>>>(ikf, iknw, iknb);
    rope_half_kernel<<<S * 32 / 256, 256, 0, stream>>>(ikf, fcos, fsin, 1, 128);
    rotate_kernel<<<S * NH, 128, 0, stream>>>(iqf, iqr);
    rotate_kernel<<<S, 128, 0, stream>>>(ikf, ikr);
    // iw = (x @ idx_weights_proj.T) * 0.25
    gemm_nt<<<dim3(1, S / 64), 256, 0, stream>>>(x, idx_wp, iw, S, 16, DIM, 0.25f);
    // wq in place over iqr
    wq_kernel<<<S * NH * 128 / 256, 256, 0, stream>>>(iw, iqr);
    // index scores (causal lower-triangle tiles only), then per-row top-k
    iscore_kernel<<<dim3(32, 32), 256, 0, stream>>>(iqr, ikr, isc);
    topk_kernel<<<S, 256, 0, stream>>>(isc, tk);
    // fused sparse attention -> o2
    attn_kernel<<<dim3(S, NH), 256, 0, stream>>>(q, kv, kvp, kv_b, tk, o2);
    // out = o2 @ o_proj.T
    gemm_nt<<<dim3(DIM / 64, S / 64), 256, 0, stream>>>(o2, o_proj, out, S, DIM, NH * V_HD, 1.f);
}

// Round 2
// 5620.025 us; speedup vs baseline: 1.6073x; 1.6073x over previous
//
#include <hip/hip_runtime.h>
#include <hip/hip_bf16.h>
#include <math.h>

#define S 2048
#define NH 16
#define DIM 2048
#define QK_NOPE 128
#define QK_ROPE 64
#define QK_HD 192
#define V_HD 128
#define Q_LORA 1536
#define KV_LORA 512
#define IDX_HD 128
#define SM_SCALE 0.07216878364870323f
#define SCHUNK 512

typedef __hip_bfloat16 bf16;

// ---------------- generic f32 GEMM: C[M,N] = alpha * A[M,K] @ B[N,K]^T ----------------
__global__ __launch_bounds__(256) void gemm_nt(const float* __restrict__ A,
                                               const float* __restrict__ B,
                                               float* __restrict__ C,
                                               int M, int N, int K, float alpha) {
    __shared__ float As[64][17];
    __shared__ float Bs[64][17];
    const int bm = blockIdx.y * 64, bn = blockIdx.x * 64;
    const int tid = threadIdx.x;
    const int tr = (tid >> 4) << 2, tc = (tid & 15) << 2;
    float acc[4][4] = {};
    for (int k0 = 0; k0 < K; k0 += 16) {
        for (int u = 0; u < 4; ++u) {
            int idx = tid + u * 256;
            int rr = idx >> 4, cc = idx & 15;
            As[rr][cc] = A[(size_t)(bm + rr) * K + k0 + cc];
            Bs[rr][cc] = (bn + rr < N) ? B[(size_t)(bn + rr) * K + k0 + cc] : 0.f;
        }
        __syncthreads();
        for (int kk = 0; kk < 16; ++kk) {
            float a[4], b[4];
            for (int i = 0; i < 4; ++i) a[i] = As[tr + i][kk];
            for (int j = 0; j < 4; ++j) b[j] = Bs[tc + j][kk];
            for (int i = 0; i < 4; ++i)
                for (int j = 0; j < 4; ++j) acc[i][j] += a[i] * b[j];
        }
        __syncthreads();
    }
    for (int i = 0; i < 4; ++i)
        for (int j = 0; j < 4; ++j)
            if (bn + tc + j < N)
                C[(size_t)(bm + tr + i) * N + bn + tc + j] = alpha * acc[i][j];
}

// ---------------- RMSNorm ----------------
__global__ __launch_bounds__(256) void rms_kernel(const float* __restrict__ in, float* __restrict__ out,
                                                  const float* __restrict__ w, int C, int ldin, int ldout) {
    const int row = blockIdx.x;
    const float* xr = in + (size_t)row * ldin;
    float* yr = out + (size_t)row * ldout;
    float ss = 0.f;
    for (int c = threadIdx.x; c < C; c += 256) { float v = xr[c]; ss += v * v; }
    for (int o = 32; o; o >>= 1) ss += __shfl_down(ss, o, 64);
    __shared__ float red[4];
    const int wave = threadIdx.x >> 6, lane = threadIdx.x & 63;
    if (lane == 0) red[wave] = ss;
    __syncthreads();
    const float tot = red[0] + red[1] + red[2] + red[3];
    const float scale = rsqrtf(tot / (float)C + 1e-6f);
    for (int c = threadIdx.x; c < C; c += 256) yr[c] = w[c] * (xr[c] * scale);
}

// ---------------- LayerNorm (row length 128) ----------------
__global__ __launch_bounds__(128) void ln_kernel(float* __restrict__ x, const float* __restrict__ w,
                                                 const float* __restrict__ b) {
    const int row = blockIdx.x;
    float* xr = x + (size_t)row * 128;
    const int tid = threadIdx.x;
    float v = xr[tid];
    float sm = v;
    for (int o = 32; o; o >>= 1) sm += __shfl_down(sm, o, 64);
    __shared__ float red[2];
    if ((tid & 63) == 0) red[tid >> 6] = sm;
    __syncthreads();
    const float mu = (red[0] + red[1]) * (1.f / 128.f);
    __syncthreads();
    float d = v - mu;
    float sv = d * d;
    for (int o = 32; o; o >>= 1) sv += __shfl_down(sv, o, 64);
    if ((tid & 63) == 0) red[tid >> 6] = sv;
    __syncthreads();
    const float var = (red[0] + red[1]) * (1.f / 128.f);
    const float rs = rsqrtf(var + 1e-6f);
    xr[tid] = (v - mu) * rs * w[tid] + b[tid];
}

// ---------------- RoPE interleaved ----------------
__global__ __launch_bounds__(256) void rope_inter_kernel(float* __restrict__ X, const float* __restrict__ ct,
                                                         const float* __restrict__ st, int H, int hs, int off) {
    int idx = blockIdx.x * 256 + threadIdx.x;
    int k = idx & 31;
    int h = (idx >> 5) % H;
    int s = idx / (32 * H);
    if (s >= S) return;
    float c = ct[s * 32 + k], sn = st[s * 32 + k];
    float* p = X + ((size_t)s * H + h) * hs + off;
    float x1 = p[2 * k], x2 = p[2 * k + 1];
    p[2 * k]     = x1 * c - x2 * sn;
    p[2 * k + 1] = x1 * sn + x2 * c;
}

// ---------------- RoPE half ----------------
__global__ __launch_bounds__(256) void rope_half_kernel(float* __restrict__ X, const float* __restrict__ ct,
                                                        const float* __restrict__ st, int H, int hs) {
    int idx = blockIdx.x * 256 + threadIdx.x;
    int k = idx & 31;
    int h = (idx >> 5) % H;
    int s = idx / (32 * H);
    if (s >= S) return;
    float c = ct[s * 32 + k], sn = st[s * 32 + k];
    float* p = X + ((size_t)s * H + h) * hs;
    float x1 = p[k], x2 = p[32 + k];
    p[k]      = x1 * c - x2 * sn;
    p[32 + k] = x1 * sn + x2 * c;
}

// ---------------- Hadamard rotate ----------------
__global__ __launch_bounds__(128) void rotate_kernel(const float* __restrict__ in, bf16* __restrict__ out) {
    __shared__ float xs[128];
    const int r = blockIdx.x, j = threadIdx.x;
    float v = in[(size_t)r * 128 + j];
    xs[j] = __bfloat162float(__float2bfloat16(v));
    __syncthreads();
    float acc = 0.f;
    for (int d = 0; d < 128; ++d) {
        float xv = xs[d];
        acc += (__popc(d & j) & 1) ? -xv : xv;
    }
    float t = __bfloat162float(__float2bfloat16(acc)) * 0.08838834764831845f;
    out[(size_t)r * 128 + j] = __float2bfloat16(t);
}

// ---------------- wq scale ----------------
__global__ __launch_bounds__(256) void wq_kernel(const float* __restrict__ iw, bf16* __restrict__ iqr) {
    int idx = blockIdx.x * 256 + threadIdx.x;
    int sh = idx >> 7;
    float a = iw[sh];
    float v = __bfloat162float(iqr[idx]);
    float t = (a * v) * 0.08838834764831845f;
    iqr[idx] = __float2bfloat16(t);
}

// ---------------- index score ----------------
__global__ __launch_bounds__(256) void iscore_kernel(const bf16* __restrict__ wq, const bf16* __restrict__ ik,
                                                     float* __restrict__ out) {
    const int bt = blockIdx.x * 64, bs = blockIdx.y * 64;
    if (bs + 63 < bt) return;
    __shared__ float As[64][17];
    __shared__ float Bs[64][17];
    const int tid = threadIdx.x;
    const int tr = (tid >> 4) << 2, tc = (tid & 15) << 2;
    float acc[4][4] = {};
    for (int h = 0; h < 16; ++h) {
        float acch[4][4] = {};
        for (int k0 = 0; k0 < 128; k0 += 16) {
            for (int u = 0; u < 4; ++u) {
                int idx = tid + u * 256;
                int rr = idx >> 4, cc = idx & 15;
                As[rr][cc] = __bfloat162float(wq[(size_t)(bs + rr) * 2048 + h * 128 + k0 + cc]);
                Bs[rr][cc] = __bfloat162float(ik[(size_t)(bt + rr) * 128 + k0 + cc]);
            }
            __syncthreads();
            for (int kk = 0; kk < 16; ++kk) {
                float a[4], b[4];
                for (int i = 0; i < 4; ++i) a[i] = As[tr + i][kk];
                for (int j = 0; j < 4; ++j) b[j] = Bs[tc + j][kk];
                for (int i = 0; i < 4; ++i)
                    for (int j = 0; j < 4; ++j) acch[i][j] += a[i] * b[j];
            }
            __syncthreads();
        }
        for (int i = 0; i < 4; ++i)
            for (int j = 0; j < 4; ++j) acc[i][j] += fmaxf(acch[i][j], 0.f);
    }
    for (int i = 0; i < 4; ++i)
        for (int j = 0; j < 4; ++j)
            out[(size_t)(bs + tr + i) * 2048 + bt + tc + j] = acc[i][j];
}

// ---------------- top-k ----------------
__global__ __launch_bounds__(256) void topk_kernel(const float* __restrict__ isc, int* __restrict__ tk) {
    __shared__ unsigned long long keys[2048];
    const int s = blockIdx.x;
    const float* row = isc + (size_t)s * 2048;
    for (int t = threadIdx.x; t < 2048; t += 256) {
        unsigned long long kk = 0ull;
        if (t <= s) {
            unsigned int vb = __float_as_uint(row[t]);
            kk = ((unsigned long long)vb << 32) | (unsigned int)(2048 - t);
        }
        keys[t] = kk;
    }
    __syncthreads();
    for (int k = 2; k <= 2048; k <<= 1) {
        for (int j = k >> 1; j > 0; j >>= 1) {
            for (int t = threadIdx.x; t < 2048; t += 256) {
                int l = t ^ j;
                if (l > t) {
                    bool up = ((t & k) == 0);
                    unsigned long long a = keys[t], b = keys[l];
                    bool sw = up ? (a < b) : (a > b);
                    if (sw) { keys[t] = b; keys[l] = a; }
                }
            }
            __syncthreads();
        }
    }
    const int cnt = min(1024, s + 1);
    for (int i = threadIdx.x; i < 1024; i += 256) {
        int t = (i < cnt) ? (2048 - (int)(keys[i] & 0xFFFFFFFFull)) : -1;
        tk[(size_t)s * 1024 + i] = t;
    }
}

// ---------------- qabs: qa_all[s][h][c] = sm_scale * sum_d q[s,h,d]*kv_b[h*256+d][c], c<512 ----------------
__global__ __launch_bounds__(256) void qabs_kernel(const float* __restrict__ q, const float* __restrict__ kv_b,
                                                   float* __restrict__ qa_all) {
    __shared__ float As[64][17];
    __shared__ float Bs[16][65];
    const int c0 = blockIdx.x * 64, s0 = blockIdx.y * 64, h = blockIdx.z;
    const int tid = threadIdx.x;
    const int tr = (tid >> 4) << 2, tc = (tid & 15) << 2;
    float acc[4][4] = {};
    for (int k0 = 0; k0 < 128; k0 += 16) {
        for (int u = 0; u < 4; ++u) {
            int idx = tid + u * 256;
            int rr = idx >> 4, cc = idx & 15;
            As[rr][cc] = q[(size_t)(s0 + rr) * (NH * QK_HD) + h * QK_HD + k0 + cc];
            int rr2 = idx >> 6, cc2 = idx & 63;
            Bs[rr2][cc2] = kv_b[(size_t)(h * 256 + k0 + rr2) * 512 + c0 + cc2];
        }
        __syncthreads();
        for (int kk = 0; kk < 16; ++kk) {
            float a[4], b[4];
            for (int i = 0; i < 4; ++i) a[i] = As[tr + i][kk];
            for (int j = 0; j < 4; ++j) b[j] = Bs[kk][tc + j];
            for (int i = 0; i < 4; ++i)
                for (int j = 0; j < 4; ++j) acc[i][j] += a[i] * b[j];
        }
        __syncthreads();
    }
    for (int i = 0; i < 4; ++i)
        for (int j = 0; j < 4; ++j)
            qa_all[((size_t)(s0 + tr + i) * 16 + h) * 576 + c0 + tc + j] = acc[i][j] * SM_SCALE;
}

// ---------------- qpe_fill: qa_all[s][h][512+r] = q[s,h,128+r] * sm_scale ----------------
__global__ __launch_bounds__(256) void qpe_fill(const float* __restrict__ q, float* __restrict__ qa_all) {
    int idx = blockIdx.x * 256 + threadIdx.x;
    int r = idx & 63, h = (idx >> 6) & 15, s = idx >> 10;
    qa_all[((size_t)s * 16 + h) * 576 + 512 + r] = q[((size_t)s * 16 + h) * 192 + 128 + r] * SM_SCALE;
}

// ---------------- attn_score: per block one s; 16 heads x 1024 gathered keys; K=576 ----------------
__global__ __launch_bounds__(512) void attn_score(const float* __restrict__ qa_all, const float* __restrict__ kv,
                                                  const float* __restrict__ kvp, const int* __restrict__ tk,
                                                  float* __restrict__ scb, int s0) {
    const int s = s0 + blockIdx.x;
    const int sl = blockIdx.x;
    const int tid = threadIdx.x;
    __shared__ int tks[1024];
    __shared__ float qa[16][576];
    __shared__ float kvs[256][20];
    const int cnt = min(1024, s + 1);
    for (int j = tid; j < 1024; j += 512) {
        int t = tk[(size_t)s * 1024 + j];
        tks[j] = t < 0 ? 0 : t;
    }
    {
        const float4* src = (const float4*)(qa_all + (size_t)s * 16 * 576);
        float4* dst = (float4*)&qa[0][0];
        for (int i = tid; i < 16 * 576 / 4; i += 512) dst[i] = src[i];
    }
    __syncthreads();
    const int lane = tid & 63, grp = tid >> 6;
    const int kb = grp & 3, hb = grp >> 2;
    const int key = 64 * kb + lane;
    const int r = tid >> 1, half = tid & 1;
    for (int tile = 0; tile < 4; ++tile) {
        float acc[8] = {};
        const int jg_r = tile * 256 + r;
        const int t_r = tks[jg_r];
        for (int chunk = 0; chunk < 36; ++chunk) {
            const int kk0 = chunk * 16;
            const float* src = (kk0 < 512) ? (kv + (size_t)t_r * 512 + kk0)
                                           : (kvp + (size_t)t_r * 576 + kk0);
            float4 f0 = ((const float4*)src)[half * 2];
            float4 f1 = ((const float4*)src)[half * 2 + 1];
            *(float4*)&kvs[r][half * 8]     = f0;
            *(float4*)&kvs[r][half * 8 + 4] = f1;
            __syncthreads();
            for (int kk4 = 0; kk4 < 4; ++kk4) {
                float4 b4 = *(const float4*)&kvs[key][kk4 * 4];
                for (int i = 0; i < 8; ++i) {
                    float4 a4 = *(const float4*)&qa[hb * 8 + i][kk0 + kk4 * 4];
                    acc[i] += a4.x * b4.x + a4.y * b4.y + a4.z * b4.z + a4.w * b4.w;
                }
            }
            __syncthreads();
        }
        const int jg = tile * 256 + key;
        for (int i = 0; i < 8; ++i)
            scb[((size_t)sl * 16 + hb * 8 + i) * 1024 + jg] = (jg < cnt) ? acc[i] : -1e30f;
    }
}

// ---------------- attn_pv: per block one s; softmax stats + PV GEMM -> o1 ----------------
__global__ __launch_bounds__(512) void attn_pv(const float* __restrict__ scb, const float* __restrict__ kv,
                                               const int* __restrict__ tk, float* __restrict__ o1, int s0) {
    const int s = s0 + blockIdx.x;
    const int sl = blockIdx.x;
    const int tid = threadIdx.x;
    const int lane = tid & 63, wave = tid >> 6;
    __shared__ int tks[1024];
    __shared__ float kvs2[16][512];
    __shared__ float pst[16][16];
    __shared__ float m_s[16], il_s[16];
    for (int j = tid; j < 1024; j += 512) {
        int t = tk[(size_t)s * 1024 + j];
        tks[j] = t < 0 ? 0 : t;
    }
    // softmax stats: wave w handles rows w and w+8
    for (int h = wave; h < 16; h += 8) {
        const float* row = scb + ((size_t)sl * 16 + h) * 1024;
        float v[16];
        float m = -INFINITY;
        for (int i = 0; i < 16; ++i) { v[i] = row[lane + 64 * i]; m = fmaxf(m, v[i]); }
        for (int o = 32; o; o >>= 1) m = fmaxf(m, __shfl_down(m, o, 64));
        m = __shfl(m, 0, 64);
        float l = 0.f;
        for (int i = 0; i < 16; ++i) l += __expf(v[i] - m);
        for (int o = 32; o; o >>= 1) l += __shfl_down(l, o, 64);
        if (lane == 0) { m_s[h] = m; il_s[h] = 1.f / l; }
    }
    __syncthreads();
    float acc[16] = {};
    const int c = tid;
    const int jrow = tid >> 5, seg = tid & 31;
    for (int j0 = 0; j0 < 1024; j0 += 16) {
        // stage kv rows
        {
            const int t = tks[j0 + jrow];
            const float4* src = (const float4*)(kv + (size_t)t * 512);
            float4* dst = (float4*)&kvs2[jrow][seg * 16];
            for (int u = 0; u < 4; ++u) dst[u] = src[seg * 4 + u];
        }
        // stage p
        if (tid < 256) {
            int j = tid & 15, h = tid >> 4;
            float v = scb[((size_t)sl * 16 + h) * 1024 + j0 + j];
            pst[h][j] = __expf(v - m_s[h]) * il_s[h];
        }
        __syncthreads();
        for (int jq = 0; jq < 4; ++jq) {
            float b0 = kvs2[jq * 4 + 0][c];
            float b1 = kvs2[jq * 4 + 1][c];
            float b2 = kvs2[jq * 4 + 2][c];
            float b3 = kvs2[jq * 4 + 3][c];
            for (int h = 0; h < 16; ++h) {
                float4 p4 = *(const float4*)&pst[h][jq * 4];
                acc[h] += p4.x * b0 + p4.y * b1 + p4.z * b2 + p4.w * b3;
            }
        }
        __syncthreads();
    }
    for (int h = 0; h < 16; ++h)
        o1[((size_t)sl * 16 + h) * 512 + c] = acc[h];
}

// ---------------- outproj: o2[s0+sl][h*128+d] = sum_c o1[sl,h,c] * kv_b[h*256+128+d][c] ----------------
__global__ __launch_bounds__(256) void outproj_kernel(const float* __restrict__ o1, const float* __restrict__ kv_b,
                                                      float* __restrict__ o2, int s0) {
    __shared__ float As[64][17];
    __shared__ float Bs[64][17];
    const int n0 = blockIdx.x * 64, sl0 = blockIdx.y * 64, h = blockIdx.z;
    const int tid = threadIdx.x;
    const int tr = (tid >> 4) << 2, tc = (tid & 15) << 2;
    float acc[4][4] = {};
    for (int k0 = 0; k0 < 512; k0 += 16) {
        for (int u = 0; u < 4; ++u) {
            int idx = tid + u * 256;
            int rr = idx >> 4, cc = idx & 15;
            As[rr][cc] = o1[((size_t)(sl0 + rr) * 16 + h) * 512 + k0 + cc];
            Bs[rr][cc] = kv_b[(size_t)(h * 256 + 128 + n0 + rr) * 512 + k0 + cc];
        }
        __syncthreads();
        for (int kk = 0; kk < 16; ++kk) {
            float a[4], b[4];
            for (int i = 0; i < 4; ++i) a[i] = As[tr + i][kk];
            for (int j = 0; j < 4; ++j) b[j] = Bs[tc + j][kk];
            for (int i = 0; i < 4; ++i)
                for (int j = 0; j < 4; ++j) acc[i][j] += a[i] * b[j];
        }
        __syncthreads();
    }
    for (int i = 0; i < 4; ++i)
        for (int j = 0; j < 4; ++j)
            o2[(size_t)(s0 + sl0 + tr + i) * 2048 + h * 128 + n0 + tc + j] = acc[i][j];
}

extern "C" void kernel_launch(void* const* d_in, const int* in_sizes, int n_in,
                              void* d_out, int out_size, void* d_ws, size_t ws_size,
                              hipStream_t stream) {
    const float* x         = (const float*)d_in[0];
    const float* fcos      = (const float*)d_in[2];
    const float* fsin      = (const float*)d_in[3];
    const float* q_a_proj  = (const float*)d_in[5];
    const float* q_a_ln_w  = (const float*)d_in[6];
    const float* q_b_proj  = (const float*)d_in[7];
    const float* kv_a_proj = (const float*)d_in[8];
    const float* kv_a_ln_w = (const float*)d_in[9];
    const float* kv_b      = (const float*)d_in[10];
    const float* o_proj    = (const float*)d_in[11];
    const float* idx_wq_b  = (const float*)d_in[12];
    const float* idx_wk    = (const float*)d_in[13];
    const float* iknw      = (const float*)d_in[14];
    const float* iknb      = (const float*)d_in[15];
    const float* idx_wp    = (const float*)d_in[16];
    float* out = (float*)d_out;

    char* ws = (char*)d_ws;
    size_t off = 0;
    auto alloc = [&](size_t bytes) {
        char* p = ws + off;
        off += (bytes + 255) & ~(size_t)255;
        return p;
    };
    // Region A: dead by attention time; overlaid by scb/o1c.
    float* qr  = (float*)alloc((size_t)S * Q_LORA * 4);       // 12.6 MB
    float* q   = (float*)alloc((size_t)S * NH * QK_HD * 4);   // 25.2 MB
    float* R1  = (float*)alloc((size_t)S * 2048 * 4);         // 16.8 MB (iqf / isc)
    float* iqf = R1;
    float* isc = R1;
    float* ikf = (float*)alloc((size_t)S * 128 * 4);
    float* iw  = (float*)alloc((size_t)S * 16 * 4);
    bf16* iqr  = (bf16*)alloc((size_t)S * 2048 * 2);
    bf16* ikr  = (bf16*)alloc((size_t)S * 128 * 2);
    // Persistent-through-attention buffers:
    int* tk      = (int*)alloc((size_t)S * 1024 * 4);         // 8.4 MB
    float* kvp   = (float*)alloc((size_t)S * 576 * 4);        // 4.7 MB
    float* kv    = (float*)alloc((size_t)S * KV_LORA * 4);    // 4.2 MB
    float* qa_all= (float*)alloc((size_t)S * 16 * 576 * 4);   // 75.5 MB
    float* o2    = (float*)alloc((size_t)S * 2048 * 4);       // 16.8 MB
    // Aliases over region A (qr/q/R1 all dead before attention chunks run):
    float* scb = (float*)ws;                                  // 32 MiB  (512*16*1024 f32)
    float* o1c = (float*)(ws + (size_t)32 * 1024 * 1024);     // 16 MiB  (512*16*512 f32)

    // ---- projections ----
    gemm_nt<<<dim3(Q_LORA / 64, S / 64), 256, 0, stream>>>(x, q_a_proj, qr, S, Q_LORA, DIM, 1.f);
    rms_kernel<<<S, 256, 0, stream>>>(qr, qr, q_a_ln_w, Q_LORA, Q_LORA, Q_LORA);
    gemm_nt<<<dim3(NH * QK_HD / 64, S / 64), 256, 0, stream>>>(qr, q_b_proj, q, S, NH * QK_HD, Q_LORA, 1.f);
    gemm_nt<<<dim3(576 / 64, S / 64), 256, 0, stream>>>(x, kv_a_proj, kvp, S, 576, DIM, 1.f);
    rms_kernel<<<S, 256, 0, stream>>>(kvp, kv, kv_a_ln_w, KV_LORA, 576, KV_LORA);
    rope_inter_kernel<<<S * NH * 32 / 256, 256, 0, stream>>>(q, fcos, fsin, NH, QK_HD, QK_NOPE);
    rope_inter_kernel<<<S * 32 / 256, 256, 0, stream>>>(kvp, fcos, fsin, 1, 576, KV_LORA);
    // ---- indexer ----
    gemm_nt<<<dim3(2048 / 64, S / 64), 256, 0, stream>>>(qr, idx_wq_b, iqf, S, 2048, Q_LORA, 1.f);
    rope_half_kernel<<<S * NH * 32 / 256, 256, 0, stream>>>(iqf, fcos, fsin, NH, 128);
    gemm_nt<<<dim3(2, S / 64), 256, 0, stream>>>(x, idx_wk, ikf, S, 128, DIM, 1.f);
    ln_kernel<<<S, 128, 0, stream>>>(ikf, iknw, iknb);
    rope_half_kernel<<<S * 32 / 256, 256, 0, stream>>>(ikf, fcos, fsin, 1, 128);
    rotate_kernel<<<S * NH, 128, 0, stream>>>(iqf, iqr);
    rotate_kernel<<<S, 128, 0, stream>>>(ikf, ikr);
    gemm_nt<<<dim3(1, S / 64), 256, 0, stream>>>(x, idx_wp, iw, S, 16, DIM, 0.25f);
    wq_kernel<<<S * NH * 128 / 256, 256, 0, stream>>>(iw, iqr);
    iscore_kernel<<<dim3(32, 32), 256, 0, stream>>>(iqr, ikr, isc);
    topk_kernel<<<S, 256, 0, stream>>>(isc, tk);
    // ---- attention ----
    qabs_kernel<<<dim3(8, 32, 16), 256, 0, stream>>>(q, kv_b, qa_all);
    qpe_fill<<<S * NH * 64 / 256, 256, 0, stream>>>(q, qa_all);
    for (int c = 0; c < 4; ++c) {
        int s0 = c * SCHUNK;
        attn_score<<<SCHUNK, 512, 0, stream>>>(qa_all, kv, kvp, tk, scb, s0);
        attn_pv<<<SCHUNK, 512, 0, stream>>>(scb, kv, tk, o1c, s0);
        outproj_kernel<<<dim3(2, 8, 16), 256, 0, stream>>>(o1c, kv_b, o2, s0);
    }
    gemm_nt<<<dim3(DIM / 64, S / 64), 256, 0, stream>>>(o2, o_proj, out, S, DIM, NH * V_HD, 1.f);
}

// Round 3
// 4107.763 us; speedup vs baseline: 2.1990x; 1.3681x over previous
//
#include <hip/hip_runtime.h>
#include <hip/hip_bf16.h>
#include <math.h>

#define S 2048
#define NH 16
#define DIM 2048
#define QK_NOPE 128
#define QK_ROPE 64
#define QK_HD 192
#define V_HD 128
#define Q_LORA 1536
#define KV_LORA 512
#define IDX_HD 128
#define SM_SCALE 0.07216878364870323f
#define SCHUNK 512
#define PADK 40

typedef __hip_bfloat16 bf16;
typedef __attribute__((ext_vector_type(8))) short short8;
typedef __attribute__((ext_vector_type(4))) float f32x4;

__device__ __forceinline__ f32x4 mfma_bf16(short8 a, short8 b, f32x4 c) {
    return __builtin_amdgcn_mfma_f32_16x16x32_bf16(a, b, c, 0, 0, 0);
}
__device__ __forceinline__ void async16(const void* g, void* l) {
    __builtin_amdgcn_global_load_lds((const __attribute__((address_space(1))) void*)g,
                                     (__attribute__((address_space(3))) void*)l, 16, 0, 0);
}
__device__ __forceinline__ unsigned short f2bf(float f) {  // RNE
    unsigned int u = __float_as_uint(f);
    return (unsigned short)((u + 0x7fff + ((u >> 16) & 1)) >> 16);
}
__device__ __forceinline__ float bf2f(unsigned short b) {
    return __uint_as_float(((unsigned int)b) << 16);
}

// ---------------- bf16x3 split MFMA GEMM: C[M,N] = alpha * A[M,K]f32 @ B[N,K]f32^T ----------------
// M%128==0, K%32==0; N arbitrary (load/store guarded).
__global__ __launch_bounds__(256) void gemm3_bt(const float* __restrict__ A, const float* __restrict__ B,
                                                float* __restrict__ C, int M, int N, int K, float alpha) {
    __shared__ unsigned short Ah[128 * PADK], Al[128 * PADK], Bh[128 * PADK], Bl[128 * PADK];
    const int tid = threadIdx.x;
    const int bm = blockIdx.y * 128, bn = blockIdx.x * 128;
    const int w = tid >> 6, lane = tid & 63;
    const int wm = (w >> 1) * 64, wn = (w & 1) * 64;
    const int fr = lane & 15, fk = (lane >> 4) * 8;
    f32x4 acc[4][4];
    for (int i = 0; i < 4; ++i)
        for (int j = 0; j < 4; ++j) acc[i][j] = f32x4{0.f, 0.f, 0.f, 0.f};
    for (int k0 = 0; k0 < K; k0 += 32) {
        __syncthreads();
        for (int it = 0; it < 4; ++it) {
            int f = it * 256 + tid;            // float4 index in 128x32 tile
            int row = f >> 3, kc = (f & 7) * 4;
            float4 av = *(const float4*)(A + (size_t)(bm + row) * K + k0 + kc);
            float4 bv = make_float4(0.f, 0.f, 0.f, 0.f);
            if (bn + row < N) bv = *(const float4*)(B + (size_t)(bn + row) * K + k0 + kc);
            ushort4 ahi, alo, bhi, blo;
            ahi.x = f2bf(av.x); alo.x = f2bf(av.x - bf2f(ahi.x));
            ahi.y = f2bf(av.y); alo.y = f2bf(av.y - bf2f(ahi.y));
            ahi.z = f2bf(av.z); alo.z = f2bf(av.z - bf2f(ahi.z));
            ahi.w = f2bf(av.w); alo.w = f2bf(av.w - bf2f(ahi.w));
            bhi.x = f2bf(bv.x); blo.x = f2bf(bv.x - bf2f(bhi.x));
            bhi.y = f2bf(bv.y); blo.y = f2bf(bv.y - bf2f(bhi.y));
            bhi.z = f2bf(bv.z); blo.z = f2bf(bv.z - bf2f(bhi.z));
            bhi.w = f2bf(bv.w); blo.w = f2bf(bv.w - bf2f(bhi.w));
            *(ushort4*)&Ah[row * PADK + kc] = ahi;
            *(ushort4*)&Al[row * PADK + kc] = alo;
            *(ushort4*)&Bh[row * PADK + kc] = bhi;
            *(ushort4*)&Bl[row * PADK + kc] = blo;
        }
        __syncthreads();
        short8 ahf[4], alf[4], bhf[4], blf[4];
        for (int i = 0; i < 4; ++i) {
            int ro = (wm + i * 16 + fr) * PADK + fk;
            ahf[i] = *(const short8*)&Ah[ro];
            alf[i] = *(const short8*)&Al[ro];
        }
        for (int j = 0; j < 4; ++j) {
            int ro = (wn + j * 16 + fr) * PADK + fk;
            bhf[j] = *(const short8*)&Bh[ro];
            blf[j] = *(const short8*)&Bl[ro];
        }
        for (int i = 0; i < 4; ++i)
            for (int j = 0; j < 4; ++j) {
                acc[i][j] = mfma_bf16(ahf[i], bhf[j], acc[i][j]);
                acc[i][j] = mfma_bf16(ahf[i], blf[j], acc[i][j]);
                acc[i][j] = mfma_bf16(alf[i], bhf[j], acc[i][j]);
            }
    }
    const int cr = (lane >> 4) * 4, cc = lane & 15;
    for (int i = 0; i < 4; ++i)
        for (int j = 0; j < 4; ++j) {
            int row = bm + wm + i * 16 + cr;
            int col = bn + wn + j * 16 + cc;
            if (col < N)
                for (int r = 0; r < 4; ++r)
                    C[(size_t)(row + r) * N + col] = alpha * acc[i][j][r];
        }
}

// ---------------- legacy f32 GEMM (only for tiny N=16 proj) ----------------
__global__ __launch_bounds__(256) void gemm_nt(const float* __restrict__ A,
                                               const float* __restrict__ B,
                                               float* __restrict__ C,
                                               int M, int N, int K, float alpha) {
    __shared__ float As[64][17];
    __shared__ float Bs[64][17];
    const int bm = blockIdx.y * 64, bn = blockIdx.x * 64;
    const int tid = threadIdx.x;
    const int tr = (tid >> 4) << 2, tc = (tid & 15) << 2;
    float acc[4][4] = {};
    for (int k0 = 0; k0 < K; k0 += 16) {
        for (int u = 0; u < 4; ++u) {
            int idx = tid + u * 256;
            int rr = idx >> 4, cc = idx & 15;
            As[rr][cc] = A[(size_t)(bm + rr) * K + k0 + cc];
            Bs[rr][cc] = (bn + rr < N) ? B[(size_t)(bn + rr) * K + k0 + cc] : 0.f;
        }
        __syncthreads();
        for (int kk = 0; kk < 16; ++kk) {
            float a[4], b[4];
            for (int i = 0; i < 4; ++i) a[i] = As[tr + i][kk];
            for (int j = 0; j < 4; ++j) b[j] = Bs[tc + j][kk];
            for (int i = 0; i < 4; ++i)
                for (int j = 0; j < 4; ++j) acc[i][j] += a[i] * b[j];
        }
        __syncthreads();
    }
    for (int i = 0; i < 4; ++i)
        for (int j = 0; j < 4; ++j)
            if (bn + tc + j < N)
                C[(size_t)(bm + tr + i) * N + bn + tc + j] = alpha * acc[i][j];
}

// ---------------- RMSNorm ----------------
__global__ __launch_bounds__(256) void rms_kernel(const float* __restrict__ in, float* __restrict__ out,
                                                  const float* __restrict__ w, int C, int ldin, int ldout) {
    const int row = blockIdx.x;
    const float* xr = in + (size_t)row * ldin;
    float* yr = out + (size_t)row * ldout;
    float ss = 0.f;
    for (int c = threadIdx.x; c < C; c += 256) { float v = xr[c]; ss += v * v; }
    for (int o = 32; o; o >>= 1) ss += __shfl_down(ss, o, 64);
    __shared__ float red[4];
    const int wave = threadIdx.x >> 6, lane = threadIdx.x & 63;
    if (lane == 0) red[wave] = ss;
    __syncthreads();
    const float tot = red[0] + red[1] + red[2] + red[3];
    const float scale = rsqrtf(tot / (float)C + 1e-6f);
    for (int c = threadIdx.x; c < C; c += 256) yr[c] = w[c] * (xr[c] * scale);
}

// ---------------- LayerNorm (row length 128) ----------------
__global__ __launch_bounds__(128) void ln_kernel(float* __restrict__ x, const float* __restrict__ w,
                                                 const float* __restrict__ b) {
    const int row = blockIdx.x;
    float* xr = x + (size_t)row * 128;
    const int tid = threadIdx.x;
    float v = xr[tid];
    float sm = v;
    for (int o = 32; o; o >>= 1) sm += __shfl_down(sm, o, 64);
    __shared__ float red[2];
    if ((tid & 63) == 0) red[tid >> 6] = sm;
    __syncthreads();
    const float mu = (red[0] + red[1]) * (1.f / 128.f);
    __syncthreads();
    float d = v - mu;
    float sv = d * d;
    for (int o = 32; o; o >>= 1) sv += __shfl_down(sv, o, 64);
    if ((tid & 63) == 0) red[tid >> 6] = sv;
    __syncthreads();
    const float var = (red[0] + red[1]) * (1.f / 128.f);
    const float rs = rsqrtf(var + 1e-6f);
    xr[tid] = (v - mu) * rs * w[tid] + b[tid];
}

// ---------------- RoPE interleaved ----------------
__global__ __launch_bounds__(256) void rope_inter_kernel(float* __restrict__ X, const float* __restrict__ ct,
                                                         const float* __restrict__ st, int H, int hs, int off) {
    int idx = blockIdx.x * 256 + threadIdx.x;
    int k = idx & 31;
    int h = (idx >> 5) % H;
    int s = idx / (32 * H);
    if (s >= S) return;
    float c = ct[s * 32 + k], sn = st[s * 32 + k];
    float* p = X + ((size_t)s * H + h) * hs + off;
    float x1 = p[2 * k], x2 = p[2 * k + 1];
    p[2 * k]     = x1 * c - x2 * sn;
    p[2 * k + 1] = x1 * sn + x2 * c;
}

// ---------------- RoPE half ----------------
__global__ __launch_bounds__(256) void rope_half_kernel(float* __restrict__ X, const float* __restrict__ ct,
                                                        const float* __restrict__ st, int H, int hs) {
    int idx = blockIdx.x * 256 + threadIdx.x;
    int k = idx & 31;
    int h = (idx >> 5) % H;
    int s = idx / (32 * H);
    if (s >= S) return;
    float c = ct[s * 32 + k], sn = st[s * 32 + k];
    float* p = X + ((size_t)s * H + h) * hs;
    float x1 = p[k], x2 = p[32 + k];
    p[k]      = x1 * c - x2 * sn;
    p[32 + k] = x1 * sn + x2 * c;
}

// ---------------- Hadamard rotate ----------------
__global__ __launch_bounds__(128) void rotate_kernel(const float* __restrict__ in, bf16* __restrict__ out) {
    __shared__ float xs[128];
    const int r = blockIdx.x, j = threadIdx.x;
    float v = in[(size_t)r * 128 + j];
    xs[j] = __bfloat162float(__float2bfloat16(v));
    __syncthreads();
    float acc = 0.f;
    for (int d = 0; d < 128; ++d) {
        float xv = xs[d];
        acc += (__popc(d & j) & 1) ? -xv : xv;
    }
    float t = __bfloat162float(__float2bfloat16(acc)) * 0.08838834764831845f;
    out[(size_t)r * 128 + j] = __float2bfloat16(t);
}

// ---------------- wq scale ----------------
__global__ __launch_bounds__(256) void wq_kernel(const float* __restrict__ iw, bf16* __restrict__ iqr) {
    int idx = blockIdx.x * 256 + threadIdx.x;
    int sh = idx >> 7;
    float a = iw[sh];
    float v = __bfloat162float(iqr[idx]);
    float t = (a * v) * 0.08838834764831845f;
    iqr[idx] = __float2bfloat16(t);
}

// ---------------- index score via bf16 MFMA (exact reference numerics) ----------------
// out[128x128 tile] = sum_h relu( wq_h[128x128] @ ik[128x128]^T ), causal tiles only
__global__ __launch_bounds__(256) void iscore_mfma(const bf16* __restrict__ wq, const bf16* __restrict__ ik,
                                                   float* __restrict__ out) {
    if (blockIdx.x > blockIdx.y) return;
    __shared__ unsigned short As[128 * 32], Bs[128 * 32];
    const int bs = blockIdx.y * 128, bt = blockIdx.x * 128;
    const int tid = threadIdx.x, w = tid >> 6, lane = tid & 63;
    const int wm = (w >> 1) * 64, wn = (w & 1) * 64;
    const int fr = lane & 15, fk = (lane >> 4) * 8;
    const int srow = lane >> 2, skc = (lane & 3) * 8;
    f32x4 sum[4][4];
    for (int i = 0; i < 4; ++i)
        for (int j = 0; j < 4; ++j) sum[i][j] = f32x4{0.f, 0.f, 0.f, 0.f};
    for (int h = 0; h < 16; ++h) {
        f32x4 acc[4][4];
        for (int i = 0; i < 4; ++i)
            for (int j = 0; j < 4; ++j) acc[i][j] = f32x4{0.f, 0.f, 0.f, 0.f};
        for (int k0 = 0; k0 < 128; k0 += 32) {
            __syncthreads();
            for (int i = 0; i < 2; ++i) {
                int seg = i * 4 + w;
                async16(wq + (size_t)(bs + seg * 16 + srow) * 2048 + h * 128 + k0 + skc, &As[seg * 512]);
                async16(ik + (size_t)(bt + seg * 16 + srow) * 128 + k0 + skc, &Bs[seg * 512]);
            }
            __syncthreads();
            short8 af[4], bff[4];
            for (int i = 0; i < 4; ++i) af[i]  = *(const short8*)&As[(wm + i * 16 + fr) * 32 + fk];
            for (int j = 0; j < 4; ++j) bff[j] = *(const short8*)&Bs[(wn + j * 16 + fr) * 32 + fk];
            for (int i = 0; i < 4; ++i)
                for (int j = 0; j < 4; ++j)
                    acc[i][j] = mfma_bf16(af[i], bff[j], acc[i][j]);
        }
        for (int i = 0; i < 4; ++i)
            for (int j = 0; j < 4; ++j)
                for (int r = 0; r < 4; ++r)
                    sum[i][j][r] += fmaxf(acc[i][j][r], 0.f);
    }
    const int cr = (lane >> 4) * 4, cc = lane & 15;
    for (int i = 0; i < 4; ++i)
        for (int j = 0; j < 4; ++j)
            for (int r = 0; r < 4; ++r)
                out[(size_t)(bs + wm + i * 16 + cr + r) * 2048 + bt + wn + j * 16 + cc] = sum[i][j][r];
}

// ---------------- top-k ----------------
__global__ __launch_bounds__(256) void topk_kernel(const float* __restrict__ isc, int* __restrict__ tk) {
    __shared__ unsigned long long keys[2048];
    const int s = blockIdx.x;
    const float* row = isc + (size_t)s * 2048;
    for (int t = threadIdx.x; t < 2048; t += 256) {
        unsigned long long kk = 0ull;
        if (t <= s) {
            unsigned int vb = __float_as_uint(row[t]);
            kk = ((unsigned long long)vb << 32) | (unsigned int)(2048 - t);
        }
        keys[t] = kk;
    }
    __syncthreads();
    for (int k = 2; k <= 2048; k <<= 1) {
        for (int j = k >> 1; j > 0; j >>= 1) {
            for (int t = threadIdx.x; t < 2048; t += 256) {
                int l = t ^ j;
                if (l > t) {
                    bool up = ((t & k) == 0);
                    unsigned long long a = keys[t], b = keys[l];
                    bool sw = up ? (a < b) : (a > b);
                    if (sw) { keys[t] = b; keys[l] = a; }
                }
            }
            __syncthreads();
        }
    }
    const int cnt = min(1024, s + 1);
    for (int i = threadIdx.x; i < 1024; i += 256) {
        int t = (i < cnt) ? (2048 - (int)(keys[i] & 0xFFFFFFFFull)) : -1;
        tk[(size_t)s * 1024 + i] = t;
    }
}

// ---------------- qabs ----------------
__global__ __launch_bounds__(256) void qabs_kernel(const float* __restrict__ q, const float* __restrict__ kv_b,
                                                   float* __restrict__ qa_all) {
    __shared__ float As[64][17];
    __shared__ float Bs[16][65];
    const int c0 = blockIdx.x * 64, s0 = blockIdx.y * 64, h = blockIdx.z;
    const int tid = threadIdx.x;
    const int tr = (tid >> 4) << 2, tc = (tid & 15) << 2;
    float acc[4][4] = {};
    for (int k0 = 0; k0 < 128; k0 += 16) {
        for (int u = 0; u < 4; ++u) {
            int idx = tid + u * 256;
            int rr = idx >> 4, cc = idx & 15;
            As[rr][cc] = q[(size_t)(s0 + rr) * (NH * QK_HD) + h * QK_HD + k0 + cc];
            int rr2 = idx >> 6, cc2 = idx & 63;
            Bs[rr2][cc2] = kv_b[(size_t)(h * 256 + k0 + rr2) * 512 + c0 + cc2];
        }
        __syncthreads();
        for (int kk = 0; kk < 16; ++kk) {
            float a[4], b[4];
            for (int i = 0; i < 4; ++i) a[i] = As[tr + i][kk];
            for (int j = 0; j < 4; ++j) b[j] = Bs[kk][tc + j];
            for (int i = 0; i < 4; ++i)
                for (int j = 0; j < 4; ++j) acc[i][j] += a[i] * b[j];
        }
        __syncthreads();
    }
    for (int i = 0; i < 4; ++i)
        for (int j = 0; j < 4; ++j)
            qa_all[((size_t)(s0 + tr + i) * 16 + h) * 576 + c0 + tc + j] = acc[i][j] * SM_SCALE;
}

// ---------------- qpe_fill ----------------
__global__ __launch_bounds__(256) void qpe_fill(const float* __restrict__ q, float* __restrict__ qa_all) {
    int idx = blockIdx.x * 256 + threadIdx.x;
    int r = idx & 63, h = (idx >> 6) & 15, s = idx >> 10;
    qa_all[((size_t)s * 16 + h) * 576 + 512 + r] = q[((size_t)s * 16 + h) * 192 + 128 + r] * SM_SCALE;
}

// ---------------- attn_score ----------------
__global__ __launch_bounds__(512) void attn_score(const float* __restrict__ qa_all, const float* __restrict__ kv,
                                                  const float* __restrict__ kvp, const int* __restrict__ tk,
                                                  float* __restrict__ scb, int s0) {
    const int s = s0 + blockIdx.x;
    const int sl = blockIdx.x;
    const int tid = threadIdx.x;
    __shared__ int tks[1024];
    __shared__ float qa[16][576];
    __shared__ float kvs[256][20];
    const int cnt = min(1024, s + 1);
    for (int j = tid; j < 1024; j += 512) {
        int t = tk[(size_t)s * 1024 + j];
        tks[j] = t < 0 ? 0 : t;
    }
    {
        const float4* src = (const float4*)(qa_all + (size_t)s * 16 * 576);
        float4* dst = (float4*)&qa[0][0];
        for (int i = tid; i < 16 * 576 / 4; i += 512) dst[i] = src[i];
    }
    __syncthreads();
    const int lane = tid & 63, grp = tid >> 6;
    const int kb = grp & 3, hb = grp >> 2;
    const int key = 64 * kb + lane;
    const int r = tid >> 1, half = tid & 1;
    for (int tile = 0; tile < 4; ++tile) {
        float acc[8] = {};
        const int jg_r = tile * 256 + r;
        const int t_r = tks[jg_r];
        for (int chunk = 0; chunk < 36; ++chunk) {
            const int kk0 = chunk * 16;
            const float* src = (kk0 < 512) ? (kv + (size_t)t_r * 512 + kk0)
                                           : (kvp + (size_t)t_r * 576 + kk0);
            float4 f0 = ((const float4*)src)[half * 2];
            float4 f1 = ((const float4*)src)[half * 2 + 1];
            *(float4*)&kvs[r][half * 8]     = f0;
            *(float4*)&kvs[r][half * 8 + 4] = f1;
            __syncthreads();
            for (int kk4 = 0; kk4 < 4; ++kk4) {
                float4 b4 = *(const float4*)&kvs[key][kk4 * 4];
                for (int i = 0; i < 8; ++i) {
                    float4 a4 = *(const float4*)&qa[hb * 8 + i][kk0 + kk4 * 4];
                    acc[i] += a4.x * b4.x + a4.y * b4.y + a4.z * b4.z + a4.w * b4.w;
                }
            }
            __syncthreads();
        }
        const int jg = tile * 256 + key;
        for (int i = 0; i < 8; ++i)
            scb[((size_t)sl * 16 + hb * 8 + i) * 1024 + jg] = (jg < cnt) ? acc[i] : -1e30f;
    }
}

// ---------------- attn_pv ----------------
__global__ __launch_bounds__(512) void attn_pv(const float* __restrict__ scb, const float* __restrict__ kv,
                                               const int* __restrict__ tk, float* __restrict__ o1, int s0) {
    const int s = s0 + blockIdx.x;
    const int sl = blockIdx.x;
    const int tid = threadIdx.x;
    const int lane = tid & 63, wave = tid >> 6;
    __shared__ int tks[1024];
    __shared__ float kvs2[16][512];
    __shared__ float pst[16][16];
    __shared__ float m_s[16], il_s[16];
    for (int j = tid; j < 1024; j += 512) {
        int t = tk[(size_t)s * 1024 + j];
        tks[j] = t < 0 ? 0 : t;
    }
    for (int h = wave; h < 16; h += 8) {
        const float* row = scb + ((size_t)sl * 16 + h) * 1024;
        float v[16];
        float m = -INFINITY;
        for (int i = 0; i < 16; ++i) { v[i] = row[lane + 64 * i]; m = fmaxf(m, v[i]); }
        for (int o = 32; o; o >>= 1) m = fmaxf(m, __shfl_down(m, o, 64));
        m = __shfl(m, 0, 64);
        float l = 0.f;
        for (int i = 0; i < 16; ++i) l += __expf(v[i] - m);
        for (int o = 32; o; o >>= 1) l += __shfl_down(l, o, 64);
        if (lane == 0) { m_s[h] = m; il_s[h] = 1.f / l; }
    }
    __syncthreads();
    float acc[16] = {};
    const int c = tid;
    const int jrow = tid >> 5, seg = tid & 31;
    for (int j0 = 0; j0 < 1024; j0 += 16) {
        {
            const int t = tks[j0 + jrow];
            const float4* src = (const float4*)(kv + (size_t)t * 512);
            float4* dst = (float4*)&kvs2[jrow][seg * 16];
            for (int u = 0; u < 4; ++u) dst[u] = src[seg * 4 + u];
        }
        if (tid < 256) {
            int j = tid & 15, h = tid >> 4;
            float v = scb[((size_t)sl * 16 + h) * 1024 + j0 + j];
            pst[h][j] = __expf(v - m_s[h]) * il_s[h];
        }
        __syncthreads();
        for (int jq = 0; jq < 4; ++jq) {
            float b0 = kvs2[jq * 4 + 0][c];
            float b1 = kvs2[jq * 4 + 1][c];
            float b2 = kvs2[jq * 4 + 2][c];
            float b3 = kvs2[jq * 4 + 3][c];
            for (int h = 0; h < 16; ++h) {
                float4 p4 = *(const float4*)&pst[h][jq * 4];
                acc[h] += p4.x * b0 + p4.y * b1 + p4.z * b2 + p4.w * b3;
            }
        }
        __syncthreads();
    }
    for (int h = 0; h < 16; ++h)
        o1[((size_t)sl * 16 + h) * 512 + c] = acc[h];
}

// ---------------- outproj ----------------
__global__ __launch_bounds__(256) void outproj_kernel(const float* __restrict__ o1, const float* __restrict__ kv_b,
                                                      float* __restrict__ o2, int s0) {
    __shared__ float As[64][17];
    __shared__ float Bs[64][17];
    const int n0 = blockIdx.x * 64, sl0 = blockIdx.y * 64, h = blockIdx.z;
    const int tid = threadIdx.x;
    const int tr = (tid >> 4) << 2, tc = (tid & 15) << 2;
    float acc[4][4] = {};
    for (int k0 = 0; k0 < 512; k0 += 16) {
        for (int u = 0; u < 4; ++u) {
            int idx = tid + u * 256;
            int rr = idx >> 4, cc = idx & 15;
            As[rr][cc] = o1[((size_t)(sl0 + rr) * 16 + h) * 512 + k0 + cc];
            Bs[rr][cc] = kv_b[(size_t)(h * 256 + 128 + n0 + rr) * 512 + k0 + cc];
        }
        __syncthreads();
        for (int kk = 0; kk < 16; ++kk) {
            float a[4], b[4];
            for (int i = 0; i < 4; ++i) a[i] = As[tr + i][kk];
            for (int j = 0; j < 4; ++j) b[j] = Bs[tc + j][kk];
            for (int i = 0; i < 4; ++i)
                for (int j = 0; j < 4; ++j) acc[i][j] += a[i] * b[j];
        }
        __syncthreads();
    }
    for (int i = 0; i < 4; ++i)
        for (int j = 0; j < 4; ++j)
            o2[(size_t)(s0 + sl0 + tr + i) * 2048 + h * 128 + n0 + tc + j] = acc[i][j];
}

extern "C" void kernel_launch(void* const* d_in, const int* in_sizes, int n_in,
                              void* d_out, int out_size, void* d_ws, size_t ws_size,
                              hipStream_t stream) {
    const float* x         = (const float*)d_in[0];
    const float* fcos      = (const float*)d_in[2];
    const float* fsin      = (const float*)d_in[3];
    const float* q_a_proj  = (const float*)d_in[5];
    const float* q_a_ln_w  = (const float*)d_in[6];
    const float* q_b_proj  = (const float*)d_in[7];
    const float* kv_a_proj = (const float*)d_in[8];
    const float* kv_a_ln_w = (const float*)d_in[9];
    const float* kv_b      = (const float*)d_in[10];
    const float* o_proj    = (const float*)d_in[11];
    const float* idx_wq_b  = (const float*)d_in[12];
    const float* idx_wk    = (const float*)d_in[13];
    const float* iknw      = (const float*)d_in[14];
    const float* iknb      = (const float*)d_in[15];
    const float* idx_wp    = (const float*)d_in[16];
    float* out = (float*)d_out;

    char* ws = (char*)d_ws;
    size_t off = 0;
    auto alloc = [&](size_t bytes) {
        char* p = ws + off;
        off += (bytes + 255) & ~(size_t)255;
        return p;
    };
    // Region A: dead by attention-chunk time; overlaid by scb/o1c.
    float* qr  = (float*)alloc((size_t)S * Q_LORA * 4);       // 12.6 MB
    float* q   = (float*)alloc((size_t)S * NH * QK_HD * 4);   // 25.2 MB
    float* R1  = (float*)alloc((size_t)S * 2048 * 4);         // 16.8 MB (iqf / isc)
    float* iqf = R1;
    float* isc = R1;
    float* ikf = (float*)alloc((size_t)S * 128 * 4);
    float* iw  = (float*)alloc((size_t)S * 16 * 4);
    bf16* iqr  = (bf16*)alloc((size_t)S * 2048 * 2);
    bf16* ikr  = (bf16*)alloc((size_t)S * 128 * 2);
    // Persistent-through-attention buffers:
    int* tk      = (int*)alloc((size_t)S * 1024 * 4);         // 8.4 MB
    float* kvp   = (float*)alloc((size_t)S * 576 * 4);        // 4.7 MB
    float* kv    = (float*)alloc((size_t)S * KV_LORA * 4);    // 4.2 MB
    float* qa_all= (float*)alloc((size_t)S * 16 * 576 * 4);   // 75.5 MB
    float* o2    = (float*)alloc((size_t)S * 2048 * 4);       // 16.8 MB
    // Aliases over region A:
    float* scb = (float*)ws;                                  // 32 MiB
    float* o1c = (float*)(ws + (size_t)32 * 1024 * 1024);     // 16 MiB

    // ---- projections (bf16x3 MFMA) ----
    gemm3_bt<<<dim3(Q_LORA / 128, S / 128), 256, 0, stream>>>(x, q_a_proj, qr, S, Q_LORA, DIM, 1.f);
    rms_kernel<<<S, 256, 0, stream>>>(qr, qr, q_a_ln_w, Q_LORA, Q_LORA, Q_LORA);
    gemm3_bt<<<dim3(NH * QK_HD / 128, S / 128), 256, 0, stream>>>(qr, q_b_proj, q, S, NH * QK_HD, Q_LORA, 1.f);
    gemm3_bt<<<dim3(5, S / 128), 256, 0, stream>>>(x, kv_a_proj, kvp, S, 576, DIM, 1.f);
    rms_kernel<<<S, 256, 0, stream>>>(kvp, kv, kv_a_ln_w, KV_LORA, 576, KV_LORA);
    rope_inter_kernel<<<S * NH * 32 / 256, 256, 0, stream>>>(q, fcos, fsin, NH, QK_HD, QK_NOPE);
    rope_inter_kernel<<<S * 32 / 256, 256, 0, stream>>>(kvp, fcos, fsin, 1, 576, KV_LORA);
    // ---- indexer ----
    gemm3_bt<<<dim3(2048 / 128, S / 128), 256, 0, stream>>>(qr, idx_wq_b, iqf, S, 2048, Q_LORA, 1.f);
    rope_half_kernel<<<S * NH * 32 / 256, 256, 0, stream>>>(iqf, fcos, fsin, NH, 128);
    gemm3_bt<<<dim3(1, S / 128), 256, 0, stream>>>(x, idx_wk, ikf, S, 128, DIM, 1.f);
    ln_kernel<<<S, 128, 0, stream>>>(ikf, iknw, iknb);
    rope_half_kernel<<<S * 32 / 256, 256, 0, stream>>>(ikf, fcos, fsin, 1, 128);
    rotate_kernel<<<S * NH, 128, 0, stream>>>(iqf, iqr);
    rotate_kernel<<<S, 128, 0, stream>>>(ikf, ikr);
    gemm_nt<<<dim3(1, S / 64), 256, 0, stream>>>(x, idx_wp, iw, S, 16, DIM, 0.25f);
    wq_kernel<<<S * NH * 128 / 256, 256, 0, stream>>>(iw, iqr);
    iscore_mfma<<<dim3(16, 16), 256, 0, stream>>>(iqr, ikr, isc);
    topk_kernel<<<S, 256, 0, stream>>>(isc, tk);
    // ---- attention ----
    qabs_kernel<<<dim3(8, 32, 16), 256, 0, stream>>>(q, kv_b, qa_all);
    qpe_fill<<<S * NH * 64 / 256, 256, 0, stream>>>(q, qa_all);
    for (int c = 0; c < 4; ++c) {
        int s0 = c * SCHUNK;
        attn_score<<<SCHUNK, 512, 0, stream>>>(qa_all, kv, kvp, tk, scb, s0);
        attn_pv<<<SCHUNK, 512, 0, stream>>>(scb, kv, tk, o1c, s0);
        outproj_kernel<<<dim3(2, 8, 16), 256, 0, stream>>>(o1c, kv_b, o2, s0);
    }
    gemm3_bt<<<dim3(DIM / 128, S / 128), 256, 0, stream>>>(o2, o_proj, out, S, DIM, NH * V_HD, 1.f);
}

// Round 5
// 3153.833 us; speedup vs baseline: 2.8641x; 1.3025x over previous
//
#include <hip/hip_runtime.h>
#include <hip/hip_bf16.h>
#include <math.h>

#define S 2048
#define NH 16
#define DIM 2048
#define QK_NOPE 128
#define QK_ROPE 64
#define QK_HD 192
#define V_HD 128
#define Q_LORA 1536
#define KV_LORA 512
#define IDX_HD 128
#define SM_SCALE 0.07216878364870323f
#define SCHUNK 512
#define PADK 40

typedef __hip_bfloat16 bf16;
typedef unsigned short ushort_t;
typedef __attribute__((ext_vector_type(8))) short short8;
typedef __attribute__((ext_vector_type(4))) float f32x4;

__device__ __forceinline__ f32x4 mfma_bf16(short8 a, short8 b, f32x4 c) {
    return __builtin_amdgcn_mfma_f32_16x16x32_bf16(a, b, c, 0, 0, 0);
}
__device__ __forceinline__ void async16(const void* g, void* l) {
    __builtin_amdgcn_global_load_lds((const __attribute__((address_space(1))) void*)g,
                                     (__attribute__((address_space(3))) void*)l, 16, 0, 0);
}
__device__ __forceinline__ unsigned short f2bf(float f) {  // RNE
    unsigned int u = __float_as_uint(f);
    return (unsigned short)((u + 0x7fff + ((u >> 16) & 1)) >> 16);
}
__device__ __forceinline__ float bf2f(unsigned short b) {
    return __uint_as_float(((unsigned int)b) << 16);
}

// ---------------- bf16x3 split MFMA GEMM: C[M,N] = alpha * A[M,K]f32 @ B[N,K]f32^T ----------------
__global__ __launch_bounds__(256) void gemm3_bt(const float* __restrict__ A, const float* __restrict__ B,
                                                float* __restrict__ C, int M, int N, int K, float alpha) {
    __shared__ unsigned short Ah[128 * PADK], Al[128 * PADK], Bh[128 * PADK], Bl[128 * PADK];
    const int tid = threadIdx.x;
    const int bm = blockIdx.y * 128, bn = blockIdx.x * 128;
    const int w = tid >> 6, lane = tid & 63;
    const int wm = (w >> 1) * 64, wn = (w & 1) * 64;
    const int fr = lane & 15, fk = (lane >> 4) * 8;
    f32x4 acc[4][4];
    for (int i = 0; i < 4; ++i)
        for (int j = 0; j < 4; ++j) acc[i][j] = f32x4{0.f, 0.f, 0.f, 0.f};
    for (int k0 = 0; k0 < K; k0 += 32) {
        __syncthreads();
        for (int it = 0; it < 4; ++it) {
            int f = it * 256 + tid;
            int row = f >> 3, kc = (f & 7) * 4;
            float4 av = *(const float4*)(A + (size_t)(bm + row) * K + k0 + kc);
            float4 bv = make_float4(0.f, 0.f, 0.f, 0.f);
            if (bn + row < N) bv = *(const float4*)(B + (size_t)(bn + row) * K + k0 + kc);
            ushort4 ahi, alo, bhi, blo;
            ahi.x = f2bf(av.x); alo.x = f2bf(av.x - bf2f(ahi.x));
            ahi.y = f2bf(av.y); alo.y = f2bf(av.y - bf2f(ahi.y));
            ahi.z = f2bf(av.z); alo.z = f2bf(av.z - bf2f(ahi.z));
            ahi.w = f2bf(av.w); alo.w = f2bf(av.w - bf2f(ahi.w));
            bhi.x = f2bf(bv.x); blo.x = f2bf(bv.x - bf2f(bhi.x));
            bhi.y = f2bf(bv.y); blo.y = f2bf(bv.y - bf2f(bhi.y));
            bhi.z = f2bf(bv.z); blo.z = f2bf(bv.z - bf2f(bhi.z));
            bhi.w = f2bf(bv.w); blo.w = f2bf(bv.w - bf2f(bhi.w));
            *(ushort4*)&Ah[row * PADK + kc] = ahi;
            *(ushort4*)&Al[row * PADK + kc] = alo;
            *(ushort4*)&Bh[row * PADK + kc] = bhi;
            *(ushort4*)&Bl[row * PADK + kc] = blo;
        }
        __syncthreads();
        short8 ahf[4], alf[4], bhf[4], blf[4];
        for (int i = 0; i < 4; ++i) {
            int ro = (wm + i * 16 + fr) * PADK + fk;
            ahf[i] = *(const short8*)&Ah[ro];
            alf[i] = *(const short8*)&Al[ro];
        }
        for (int j = 0; j < 4; ++j) {
            int ro = (wn + j * 16 + fr) * PADK + fk;
            bhf[j] = *(const short8*)&Bh[ro];
            blf[j] = *(const short8*)&Bl[ro];
        }
        for (int i = 0; i < 4; ++i)
            for (int j = 0; j < 4; ++j) {
                acc[i][j] = mfma_bf16(ahf[i], bhf[j], acc[i][j]);
                acc[i][j] = mfma_bf16(ahf[i], blf[j], acc[i][j]);
                acc[i][j] = mfma_bf16(alf[i], bhf[j], acc[i][j]);
            }
    }
    const int cr = (lane >> 4) * 4, cc = lane & 15;
    for (int i = 0; i < 4; ++i)
        for (int j = 0; j < 4; ++j) {
            int row = bm + wm + i * 16 + cr;
            int col = bn + wn + j * 16 + cc;
            if (col < N)
                for (int r = 0; r < 4; ++r)
                    C[(size_t)(row + r) * N + col] = alpha * acc[i][j][r];
        }
}

// ---------------- legacy f32 GEMM (only for tiny N=16 proj) ----------------
__global__ __launch_bounds__(256) void gemm_nt(const float* __restrict__ A,
                                               const float* __restrict__ B,
                                               float* __restrict__ C,
                                               int M, int N, int K, float alpha) {
    __shared__ float As[64][17];
    __shared__ float Bs[64][17];
    const int bm = blockIdx.y * 64, bn = blockIdx.x * 64;
    const int tid = threadIdx.x;
    const int tr = (tid >> 4) << 2, tc = (tid & 15) << 2;
    float acc[4][4] = {};
    for (int k0 = 0; k0 < K; k0 += 16) {
        for (int u = 0; u < 4; ++u) {
            int idx = tid + u * 256;
            int rr = idx >> 4, cc = idx & 15;
            As[rr][cc] = A[(size_t)(bm + rr) * K + k0 + cc];
            Bs[rr][cc] = (bn + rr < N) ? B[(size_t)(bn + rr) * K + k0 + cc] : 0.f;
        }
        __syncthreads();
        for (int kk = 0; kk < 16; ++kk) {
            float a[4], b[4];
            for (int i = 0; i < 4; ++i) a[i] = As[tr + i][kk];
            for (int j = 0; j < 4; ++j) b[j] = Bs[tc + j][kk];
            for (int i = 0; i < 4; ++i)
                for (int j = 0; j < 4; ++j) acc[i][j] += a[i] * b[j];
        }
        __syncthreads();
    }
    for (int i = 0; i < 4; ++i)
        for (int j = 0; j < 4; ++j)
            if (bn + tc + j < N)
                C[(size_t)(bm + tr + i) * N + bn + tc + j] = alpha * acc[i][j];
}

// ---------------- RMSNorm ----------------
__global__ __launch_bounds__(256) void rms_kernel(const float* __restrict__ in, float* __restrict__ out,
                                                  const float* __restrict__ w, int C, int ldin, int ldout) {
    const int row = blockIdx.x;
    const float* xr = in + (size_t)row * ldin;
    float* yr = out + (size_t)row * ldout;
    float ss = 0.f;
    for (int c = threadIdx.x; c < C; c += 256) { float v = xr[c]; ss += v * v; }
    for (int o = 32; o; o >>= 1) ss += __shfl_down(ss, o, 64);
    __shared__ float red[4];
    const int wave = threadIdx.x >> 6, lane = threadIdx.x & 63;
    if (lane == 0) red[wave] = ss;
    __syncthreads();
    const float tot = red[0] + red[1] + red[2] + red[3];
    const float scale = rsqrtf(tot / (float)C + 1e-6f);
    for (int c = threadIdx.x; c < C; c += 256) yr[c] = w[c] * (xr[c] * scale);
}

// ---------------- LayerNorm (row length 128) ----------------
__global__ __launch_bounds__(128) void ln_kernel(float* __restrict__ x, const float* __restrict__ w,
                                                 const float* __restrict__ b) {
    const int row = blockIdx.x;
    float* xr = x + (size_t)row * 128;
    const int tid = threadIdx.x;
    float v = xr[tid];
    float sm = v;
    for (int o = 32; o; o >>= 1) sm += __shfl_down(sm, o, 64);
    __shared__ float red[2];
    if ((tid & 63) == 0) red[tid >> 6] = sm;
    __syncthreads();
    const float mu = (red[0] + red[1]) * (1.f / 128.f);
    __syncthreads();
    float d = v - mu;
    float sv = d * d;
    for (int o = 32; o; o >>= 1) sv += __shfl_down(sv, o, 64);
    if ((tid & 63) == 0) red[tid >> 6] = sv;
    __syncthreads();
    const float var = (red[0] + red[1]) * (1.f / 128.f);
    const float rs = rsqrtf(var + 1e-6f);
    xr[tid] = (v - mu) * rs * w[tid] + b[tid];
}

// ---------------- RoPE interleaved ----------------
__global__ __launch_bounds__(256) void rope_inter_kernel(float* __restrict__ X, const float* __restrict__ ct,
                                                         const float* __restrict__ st, int H, int hs, int off) {
    int idx = blockIdx.x * 256 + threadIdx.x;
    int k = idx & 31;
    int h = (idx >> 5) % H;
    int s = idx / (32 * H);
    if (s >= S) return;
    float c = ct[s * 32 + k], sn = st[s * 32 + k];
    float* p = X + ((size_t)s * H + h) * hs + off;
    float x1 = p[2 * k], x2 = p[2 * k + 1];
    p[2 * k]     = x1 * c - x2 * sn;
    p[2 * k + 1] = x1 * sn + x2 * c;
}

// ---------------- RoPE half ----------------
__global__ __launch_bounds__(256) void rope_half_kernel(float* __restrict__ X, const float* __restrict__ ct,
                                                        const float* __restrict__ st, int H, int hs) {
    int idx = blockIdx.x * 256 + threadIdx.x;
    int k = idx & 31;
    int h = (idx >> 5) % H;
    int s = idx / (32 * H);
    if (s >= S) return;
    float c = ct[s * 32 + k], sn = st[s * 32 + k];
    float* p = X + ((size_t)s * H + h) * hs;
    float x1 = p[k], x2 = p[32 + k];
    p[k]      = x1 * c - x2 * sn;
    p[32 + k] = x1 * sn + x2 * c;
}

// ---------------- Hadamard rotate ----------------
__global__ __launch_bounds__(128) void rotate_kernel(const float* __restrict__ in, bf16* __restrict__ out) {
    __shared__ float xs[128];
    const int r = blockIdx.x, j = threadIdx.x;
    float v = in[(size_t)r * 128 + j];
    xs[j] = __bfloat162float(__float2bfloat16(v));
    __syncthreads();
    float acc = 0.f;
    for (int d = 0; d < 128; ++d) {
        float xv = xs[d];
        acc += (__popc(d & j) & 1) ? -xv : xv;
    }
    float t = __bfloat162float(__float2bfloat16(acc)) * 0.08838834764831845f;
    out[(size_t)r * 128 + j] = __float2bfloat16(t);
}

// ---------------- wq scale ----------------
__global__ __launch_bounds__(256) void wq_kernel(const float* __restrict__ iw, bf16* __restrict__ iqr) {
    int idx = blockIdx.x * 256 + threadIdx.x;
    int sh = idx >> 7;
    float a = iw[sh];
    float v = __bfloat162float(iqr[idx]);
    float t = (a * v) * 0.08838834764831845f;
    iqr[idx] = __float2bfloat16(t);
}

// ---------------- index score via bf16 MFMA ----------------
__global__ __launch_bounds__(256) void iscore_mfma(const bf16* __restrict__ wq, const bf16* __restrict__ ik,
                                                   float* __restrict__ out) {
    if (blockIdx.x > blockIdx.y) return;
    __shared__ unsigned short As[128 * 32], Bs[128 * 32];
    const int bs = blockIdx.y * 128, bt = blockIdx.x * 128;
    const int tid = threadIdx.x, w = tid >> 6, lane = tid & 63;
    const int wm = (w >> 1) * 64, wn = (w & 1) * 64;
    const int fr = lane & 15, fk = (lane >> 4) * 8;
    const int srow = lane >> 2, skc = (lane & 3) * 8;
    f32x4 sum[4][4];
    for (int i = 0; i < 4; ++i)
        for (int j = 0; j < 4; ++j) sum[i][j] = f32x4{0.f, 0.f, 0.f, 0.f};
    for (int h = 0; h < 16; ++h) {
        f32x4 acc[4][4];
        for (int i = 0; i < 4; ++i)
            for (int j = 0; j < 4; ++j) acc[i][j] = f32x4{0.f, 0.f, 0.f, 0.f};
        for (int k0 = 0; k0 < 128; k0 += 32) {
            __syncthreads();
            for (int i = 0; i < 2; ++i) {
                int seg = i * 4 + w;
                async16(wq + (size_t)(bs + seg * 16 + srow) * 2048 + h * 128 + k0 + skc, &As[seg * 512]);
                async16(ik + (size_t)(bt + seg * 16 + srow) * 128 + k0 + skc, &Bs[seg * 512]);
            }
            __syncthreads();
            short8 af[4], bff[4];
            for (int i = 0; i < 4; ++i) af[i]  = *(const short8*)&As[(wm + i * 16 + fr) * 32 + fk];
            for (int j = 0; j < 4; ++j) bff[j] = *(const short8*)&Bs[(wn + j * 16 + fr) * 32 + fk];
            for (int i = 0; i < 4; ++i)
                for (int j = 0; j < 4; ++j)
                    acc[i][j] = mfma_bf16(af[i], bff[j], acc[i][j]);
        }
        for (int i = 0; i < 4; ++i)
            for (int j = 0; j < 4; ++j)
                for (int r = 0; r < 4; ++r)
                    sum[i][j][r] += fmaxf(acc[i][j][r], 0.f);
    }
    const int cr = (lane >> 4) * 4, cc = lane & 15;
    for (int i = 0; i < 4; ++i)
        for (int j = 0; j < 4; ++j)
            for (int r = 0; r < 4; ++r)
                out[(size_t)(bs + wm + i * 16 + cr + r) * 2048 + bt + wn + j * 16 + cc] = sum[i][j][r];
}

// ---------------- top-k ----------------
__global__ __launch_bounds__(256) void topk_kernel(const float* __restrict__ isc, int* __restrict__ tk) {
    __shared__ unsigned long long keys[2048];
    const int s = blockIdx.x;
    const float* row = isc + (size_t)s * 2048;
    for (int t = threadIdx.x; t < 2048; t += 256) {
        unsigned long long kk = 0ull;
        if (t <= s) {
            unsigned int vb = __float_as_uint(row[t]);
            kk = ((unsigned long long)vb << 32) | (unsigned int)(2048 - t);
        }
        keys[t] = kk;
    }
    __syncthreads();
    for (int k = 2; k <= 2048; k <<= 1) {
        for (int j = k >> 1; j > 0; j >>= 1) {
            for (int t = threadIdx.x; t < 2048; t += 256) {
                int l = t ^ j;
                if (l > t) {
                    bool up = ((t & k) == 0);
                    unsigned long long a = keys[t], b = keys[l];
                    bool sw = up ? (a < b) : (a > b);
                    if (sw) { keys[t] = b; keys[l] = a; }
                }
            }
            __syncthreads();
        }
    }
    const int cnt = min(1024, s + 1);
    for (int i = threadIdx.x; i < 1024; i += 256) {
        int t = (i < cnt) ? (2048 - (int)(keys[i] & 0xFFFFFFFFull)) : -1;
        tk[(size_t)s * 1024 + i] = t;
    }
}

// ---------------- transpose kv_b head-1 part: W1T[h][c][d] = kv_b[(h*256+d)*512+c] ----------------
__global__ __launch_bounds__(256) void w1t_kernel(const float* __restrict__ kv_b, float* __restrict__ w1t) {
    __shared__ float ts[64][65];
    const int cb = blockIdx.x * 64, db = blockIdx.y * 64, h = blockIdx.z;
    const int t = threadIdx.x;
    for (int it = 0; it < 16; ++it) {
        int idx = it * 256 + t;
        int rr = idx >> 6, cc = idx & 63;   // rr: d-local, cc: c-local
        ts[rr][cc] = kv_b[(size_t)(h * 256 + db + rr) * 512 + cb + cc];
    }
    __syncthreads();
    for (int it = 0; it < 16; ++it) {
        int idx = it * 256 + t;
        int rr = idx >> 6, cc = idx & 63;   // rr: c-local, cc: d-local
        w1t[(size_t)h * 65536 + (size_t)(cb + rr) * 128 + db + cc] = ts[cc][rr];
    }
}

// ---------------- kv split: kvh/kvl[t][576] bf16 hi/lo ----------------
__global__ __launch_bounds__(576) void kvsplit_kernel(const float* __restrict__ kv, const float* __restrict__ kvp,
                                                      ushort_t* __restrict__ kvh, ushort_t* __restrict__ kvl) {
    const int t = blockIdx.x, c = threadIdx.x;
    float v = (c < 512) ? kv[(size_t)t * 512 + c] : kvp[(size_t)t * 576 + c];
    unsigned short hi = f2bf(v);
    kvh[(size_t)t * 576 + c] = hi;
    kvl[(size_t)t * 576 + c] = f2bf(v - bf2f(hi));
}

// ---------------- qabs via bf16x3 MFMA ----------------
__global__ __launch_bounds__(256) void qabs_mfma(const float* __restrict__ q, const float* __restrict__ w1t,
                                                 ushort_t* __restrict__ qah, ushort_t* __restrict__ qal) {
    __shared__ unsigned short Ah[128 * PADK], Al[128 * PADK], Bh[128 * PADK], Bl[128 * PADK];
    const int tid = threadIdx.x;
    const int bn = blockIdx.x * 128, bm = blockIdx.y * 128, h = blockIdx.z;
    const int w = tid >> 6, lane = tid & 63;
    const int wm = (w >> 1) * 64, wn = (w & 1) * 64;
    const int fr = lane & 15, fk = (lane >> 4) * 8;
    f32x4 acc[4][4];
    for (int i = 0; i < 4; ++i)
        for (int j = 0; j < 4; ++j) acc[i][j] = f32x4{0.f, 0.f, 0.f, 0.f};
    for (int k0 = 0; k0 < 128; k0 += 32) {
        __syncthreads();
        for (int it = 0; it < 4; ++it) {
            int f = it * 256 + tid;
            int row = f >> 3, kc = (f & 7) * 4;
            float4 av = *(const float4*)(q + (size_t)(bm + row) * 3072 + h * QK_HD + k0 + kc);
            float4 bv = *(const float4*)(w1t + (size_t)h * 65536 + (size_t)(bn + row) * 128 + k0 + kc);
            ushort4 ahi, alo, bhi, blo;
            ahi.x = f2bf(av.x); alo.x = f2bf(av.x - bf2f(ahi.x));
            ahi.y = f2bf(av.y); alo.y = f2bf(av.y - bf2f(ahi.y));
            ahi.z = f2bf(av.z); alo.z = f2bf(av.z - bf2f(ahi.z));
            ahi.w = f2bf(av.w); alo.w = f2bf(av.w - bf2f(ahi.w));
            bhi.x = f2bf(bv.x); blo.x = f2bf(bv.x - bf2f(bhi.x));
            bhi.y = f2bf(bv.y); blo.y = f2bf(bv.y - bf2f(bhi.y));
            bhi.z = f2bf(bv.z); blo.z = f2bf(bv.z - bf2f(bhi.z));
            bhi.w = f2bf(bv.w); blo.w = f2bf(bv.w - bf2f(bhi.w));
            *(ushort4*)&Ah[row * PADK + kc] = ahi;
            *(ushort4*)&Al[row * PADK + kc] = alo;
            *(ushort4*)&Bh[row * PADK + kc] = bhi;
            *(ushort4*)&Bl[row * PADK + kc] = blo;
        }
        __syncthreads();
        short8 ahf[4], alf[4], bhf[4], blf[4];
        for (int i = 0; i < 4; ++i) {
            int ro = (wm + i * 16 + fr) * PADK + fk;
            ahf[i] = *(const short8*)&Ah[ro];
            alf[i] = *(const short8*)&Al[ro];
        }
        for (int j = 0; j < 4; ++j) {
            int ro = (wn + j * 16 + fr) * PADK + fk;
            bhf[j] = *(const short8*)&Bh[ro];
            blf[j] = *(const short8*)&Bl[ro];
        }
        for (int i = 0; i < 4; ++i)
            for (int j = 0; j < 4; ++j) {
                acc[i][j] = mfma_bf16(ahf[i], bhf[j], acc[i][j]);
                acc[i][j] = mfma_bf16(ahf[i], blf[j], acc[i][j]);
                acc[i][j] = mfma_bf16(alf[i], bhf[j], acc[i][j]);
            }
    }
    const int cr = (lane >> 4) * 4, cc = lane & 15;
    for (int i = 0; i < 4; ++i)
        for (int j = 0; j < 4; ++j)
            for (int r = 0; r < 4; ++r) {
                int srow = bm + wm + i * 16 + cr + r;
                int col = bn + wn + j * 16 + cc;
                float f = acc[i][j][r] * SM_SCALE;
                size_t addr = ((size_t)srow * 16 + h) * 576 + col;
                unsigned short hi = f2bf(f);
                qah[addr] = hi;
                qal[addr] = f2bf(f - bf2f(hi));
            }
}

// ---------------- qpe split ----------------
__global__ __launch_bounds__(256) void qpe_split(const float* __restrict__ q, ushort_t* __restrict__ qah,
                                                 ushort_t* __restrict__ qal) {
    int idx = blockIdx.x * 256 + threadIdx.x;
    int r = idx & 63, h = (idx >> 6) & 15, s = idx >> 10;
    float f = q[((size_t)s * 16 + h) * 192 + 128 + r] * SM_SCALE;
    size_t addr = ((size_t)s * 16 + h) * 576 + 512 + r;
    unsigned short hi = f2bf(f);
    qah[addr] = hi;
    qal[addr] = f2bf(f - bf2f(hi));
}

// ---------------- attn_score via MFMA bf16x3 ----------------
__global__ __launch_bounds__(512) void attn_score_mfma(const ushort_t* __restrict__ qah,
                                                       const ushort_t* __restrict__ qal,
                                                       const ushort_t* __restrict__ kvh,
                                                       const ushort_t* __restrict__ kvl,
                                                       const int* __restrict__ tk,
                                                       float* __restrict__ scb, int s0) {
    const int sl = blockIdx.x, s = s0 + sl;
    const int tid = threadIdx.x, w = tid >> 6, lane = tid & 63;
    __shared__ int tks[1024];
    __shared__ unsigned short kh[256 * 40], kl[256 * 40];
    const int cnt = min(1024, s + 1);
    for (int j = tid; j < 1024; j += 512) {
        int t = tk[(size_t)s * 1024 + j];
        tks[j] = t < 0 ? 0 : t;
    }
    __syncthreads();
    const int fr = lane & 15, fko = (lane >> 4) * 8;
    const size_t abase = ((size_t)s * 16 + fr) * 576 + fko;
    const int srow = tid >> 1, sseg = tid & 1;
    for (int pass = 0; pass < 4; ++pass) {
        f32x4 acc0 = {0.f, 0.f, 0.f, 0.f}, acc1 = {0.f, 0.f, 0.f, 0.f};
        for (int ch = 0; ch < 18; ++ch) {
            const int k0 = ch * 32;
            __syncthreads();
            {
                // stage 256 rows x 32 ushorts: 2 threads/row, each writes 2x int4 (16 ushorts)
                int t = tks[pass * 256 + srow];
                const ushort_t* gh = kvh + (size_t)t * 576 + k0 + sseg * 16;
                const ushort_t* gl = kvl + (size_t)t * 576 + k0 + sseg * 16;
                *(int4*)&kh[srow * 40 + sseg * 16]     = *(const int4*)gh;
                *(int4*)&kh[srow * 40 + sseg * 16 + 8] = *(const int4*)(gh + 8);
                *(int4*)&kl[srow * 40 + sseg * 16]     = *(const int4*)gl;
                *(int4*)&kl[srow * 40 + sseg * 16 + 8] = *(const int4*)(gl + 8);
            }
            __syncthreads();
            short8 ah = *(const short8*)(qah + abase + k0);
            short8 al = *(const short8*)(qal + abase + k0);
            {
                int ro = (w * 32 + fr) * 40 + fko;
                short8 bh = *(const short8*)&kh[ro];
                short8 bl = *(const short8*)&kl[ro];
                acc0 = mfma_bf16(ah, bh, acc0);
                acc0 = mfma_bf16(ah, bl, acc0);
                acc0 = mfma_bf16(al, bh, acc0);
            }
            {
                int ro = (w * 32 + 16 + fr) * 40 + fko;
                short8 bh = *(const short8*)&kh[ro];
                short8 bl = *(const short8*)&kl[ro];
                acc1 = mfma_bf16(ah, bh, acc1);
                acc1 = mfma_bf16(ah, bl, acc1);
                acc1 = mfma_bf16(al, bh, acc1);
            }
        }
        const int cr = (lane >> 4) * 4, cc = lane & 15;
        for (int r = 0; r < 4; ++r) {
            int head = cr + r;
            int key0 = pass * 256 + w * 32 + cc;
            int key1 = key0 + 16;
            scb[((size_t)sl * 16 + head) * 1024 + key0] = (key0 < cnt) ? acc0[r] : -1e30f;
            scb[((size_t)sl * 16 + head) * 1024 + key1] = (key1 < cnt) ? acc1[r] : -1e30f;
        }
    }
}

// ---------------- softmax -> p as bf16 hi/lo ----------------
__global__ __launch_bounds__(256) void softmax_pb(const float* __restrict__ scb,
                                                  ushort_t* __restrict__ pbh, ushort_t* __restrict__ pbl) {
    const size_t row = blockIdx.x;  // sl*16+h
    const float* src = scb + row * 1024;
    const int tid = threadIdx.x, wave = tid >> 6, lane = tid & 63;
    __shared__ float red[4];
    float v[4];
    float m = -INFINITY;
    for (int i = 0; i < 4; ++i) { v[i] = src[tid + 256 * i]; m = fmaxf(m, v[i]); }
    for (int o = 32; o; o >>= 1) m = fmaxf(m, __shfl_down(m, o, 64));
    if (lane == 0) red[wave] = m;
    __syncthreads();
    m = fmaxf(fmaxf(red[0], red[1]), fmaxf(red[2], red[3]));
    __syncthreads();
    float e[4], l = 0.f;
    for (int i = 0; i < 4; ++i) { e[i] = __expf(v[i] - m); l += e[i]; }
    for (int o = 32; o; o >>= 1) l += __shfl_down(l, o, 64);
    if (lane == 0) red[wave] = l;
    __syncthreads();
    const float il = 1.f / (red[0] + red[1] + red[2] + red[3]);
    for (int i = 0; i < 4; ++i) {
        float p = e[i] * il;
        unsigned short hi = f2bf(p);
        pbh[row * 1024 + tid + 256 * i] = hi;
        pbl[row * 1024 + tid + 256 * i] = f2bf(p - bf2f(hi));
    }
}

// ---------------- attn_pv via MFMA bf16x3 ----------------
__global__ __launch_bounds__(512) void attn_pv_mfma(const ushort_t* __restrict__ pbh,
                                                    const ushort_t* __restrict__ pbl,
                                                    const float* __restrict__ kv,
                                                    const int* __restrict__ tk,
                                                    float* __restrict__ o1, int s0) {
    const int sl = blockIdx.x, s = s0 + sl;
    const int tid = threadIdx.x, w = tid >> 6, lane = tid & 63;
    __shared__ int tks[1024];
    __shared__ float vt[32 * 514];
    for (int j = tid; j < 1024; j += 512) {
        int t = tk[(size_t)s * 1024 + j];
        tks[j] = t < 0 ? 0 : t;
    }
    const int fr = lane & 15, fko = (lane >> 4) * 8;
    f32x4 acc[4];
    for (int i = 0; i < 4; ++i) acc[i] = f32x4{0.f, 0.f, 0.f, 0.f};
    const size_t pbase = ((size_t)sl * 16 + fr) * 1024 + fko;
    for (int kc = 0; kc < 32; ++kc) {
        __syncthreads();
        for (int it = 0; it < 8; ++it) {
            int task = it * 512 + tid;
            int rrow = task >> 7, c4 = task & 127;
            *(float4*)&vt[rrow * 514 + c4 * 4] =
                *(const float4*)(kv + (size_t)tks[kc * 32 + rrow] * 512 + c4 * 4);
        }
        __syncthreads();
        short8 ph = *(const short8*)(pbh + pbase + kc * 32);
        short8 pl = *(const short8*)(pbl + pbase + kc * 32);
        for (int sub = 0; sub < 4; ++sub) {
            int cbase = w * 64 + sub * 16 + fr;
            short8 bh, bl;
            for (int jj = 0; jj < 8; ++jj) {
                float vv = vt[(fko + jj) * 514 + cbase];
                unsigned short hv = f2bf(vv);
                bh[jj] = (short)hv;
                bl[jj] = (short)f2bf(vv - bf2f(hv));
            }
            acc[sub] = mfma_bf16(ph, bh, acc[sub]);
            acc[sub] = mfma_bf16(pl, bh, acc[sub]);
            acc[sub] = mfma_bf16(ph, bl, acc[sub]);
        }
    }
    const int cr = (lane >> 4) * 4, cc = lane & 15;
    for (int sub = 0; sub < 4; ++sub)
        for (int r = 0; r < 4; ++r) {
            int head = cr + r, c = w * 64 + sub * 16 + cc;
            o1[((size_t)sl * 16 + head) * 512 + c] = acc[sub][r];
        }
}

// ---------------- outproj via bf16x3 MFMA ----------------
__global__ __launch_bounds__(256) void outproj_mfma(const float* __restrict__ o1, const float* __restrict__ kv_b,
                                                    float* __restrict__ o2, int s0) {
    __shared__ unsigned short Ah[128 * PADK], Al[128 * PADK], Bh[128 * PADK], Bl[128 * PADK];
    const int tid = threadIdx.x;
    const int bm = blockIdx.y * 128, h = blockIdx.z;   // bn = 0, N = 128
    const int w = tid >> 6, lane = tid & 63;
    const int wm = (w >> 1) * 64, wn = (w & 1) * 64;
    const int fr = lane & 15, fk = (lane >> 4) * 8;
    f32x4 acc[4][4];
    for (int i = 0; i < 4; ++i)
        for (int j = 0; j < 4; ++j) acc[i][j] = f32x4{0.f, 0.f, 0.f, 0.f};
    for (int k0 = 0; k0 < 512; k0 += 32) {
        __syncthreads();
        for (int it = 0; it < 4; ++it) {
            int f = it * 256 + tid;
            int row = f >> 3, kc = (f & 7) * 4;
            float4 av = *(const float4*)(o1 + ((size_t)(bm + row) * 16 + h) * 512 + k0 + kc);
            float4 bv = *(const float4*)(kv_b + (size_t)(h * 256 + 128 + row) * 512 + k0 + kc);
            ushort4 ahi, alo, bhi, blo;
            ahi.x = f2bf(av.x); alo.x = f2bf(av.x - bf2f(ahi.x));
            ahi.y = f2bf(av.y); alo.y = f2bf(av.y - bf2f(ahi.y));
            ahi.z = f2bf(av.z); alo.z = f2bf(av.z - bf2f(ahi.z));
            ahi.w = f2bf(av.w); alo.w = f2bf(av.w - bf2f(ahi.w));
            bhi.x = f2bf(bv.x); blo.x = f2bf(bv.x - bf2f(bhi.x));
            bhi.y = f2bf(bv.y); blo.y = f2bf(bv.y - bf2f(bhi.y));
            bhi.z = f2bf(bv.z); blo.z = f2bf(bv.z - bf2f(bhi.z));
            bhi.w = f2bf(bv.w); blo.w = f2bf(bv.w - bf2f(bhi.w));
            *(ushort4*)&Ah[row * PADK + kc] = ahi;
            *(ushort4*)&Al[row * PADK + kc] = alo;
            *(ushort4*)&Bh[row * PADK + kc] = bhi;
            *(ushort4*)&Bl[row * PADK + kc] = blo;
        }
        __syncthreads();
        short8 ahf[4], alf[4], bhf[4], blf[4];
        for (int i = 0; i < 4; ++i) {
            int ro = (wm + i * 16 + fr) * PADK + fk;
            ahf[i] = *(const short8*)&Ah[ro];
            alf[i] = *(const short8*)&Al[ro];
        }
        for (int j = 0; j < 4; ++j) {
            int ro = (wn + j * 16 + fr) * PADK + fk;
            bhf[j] = *(const short8*)&Bh[ro];
            blf[j] = *(const short8*)&Bl[ro];
        }
        for (int i = 0; i < 4; ++i)
            for (int j = 0; j < 4; ++j) {
                acc[i][j] = mfma_bf16(ahf[i], bhf[j], acc[i][j]);
                acc[i][j] = mfma_bf16(ahf[i], blf[j], acc[i][j]);
                acc[i][j] = mfma_bf16(alf[i], bhf[j], acc[i][j]);
            }
    }
    const int cr = (lane >> 4) * 4, cc = lane & 15;
    for (int i = 0; i < 4; ++i)
        for (int j = 0; j < 4; ++j)
            for (int r = 0; r < 4; ++r) {
                int srow = s0 + bm + wm + i * 16 + cr + r;
                int col = wn + j * 16 + cc;
                o2[(size_t)srow * 2048 + h * 128 + col] = acc[i][j][r];
            }
}

extern "C" void kernel_launch(void* const* d_in, const int* in_sizes, int n_in,
                              void* d_out, int out_size, void* d_ws, size_t ws_size,
                              hipStream_t stream) {
    const float* x         = (const float*)d_in[0];
    const float* fcos      = (const float*)d_in[2];
    const float* fsin      = (const float*)d_in[3];
    const float* q_a_proj  = (const float*)d_in[5];
    const float* q_a_ln_w  = (const float*)d_in[6];
    const float* q_b_proj  = (const float*)d_in[7];
    const float* kv_a_proj = (const float*)d_in[8];
    const float* kv_a_ln_w = (const float*)d_in[9];
    const float* kv_b      = (const float*)d_in[10];
    const float* o_proj    = (const float*)d_in[11];
    const float* idx_wq_b  = (const float*)d_in[12];
    const float* idx_wk    = (const float*)d_in[13];
    const float* iknw      = (const float*)d_in[14];
    const float* iknb      = (const float*)d_in[15];
    const float* idx_wp    = (const float*)d_in[16];
    float* out = (float*)d_out;

    char* ws = (char*)d_ws;
    size_t off = 0;
    auto alloc = [&](size_t bytes) {
        char* p = ws + off;
        off += (bytes + 255) & ~(size_t)255;
        return p;
    };
    // Region A (dead by attention-chunk phase; overlaid by scb/pbh/pbl/o1c):
    float* qr  = (float*)alloc((size_t)S * Q_LORA * 4);
    float* q   = (float*)alloc((size_t)S * NH * QK_HD * 4);
    float* R1  = (float*)alloc((size_t)S * 2048 * 4);
    float* iqf = R1;
    float* isc = R1;
    float* ikf = (float*)alloc((size_t)S * 128 * 4);
    float* iw  = (float*)alloc((size_t)S * 16 * 4);
    bf16* iqr  = (bf16*)alloc((size_t)S * 2048 * 2);
    bf16* ikr  = (bf16*)alloc((size_t)S * 128 * 2);
    // pad region A to cover chunk-phase scratch (scb 32MiB + pbh 16 + pbl 16 + o1c 16 = 80 MiB)
    const size_t CHUNK_BYTES = (size_t)SCHUNK * 16 * 1024 * 4 + (size_t)SCHUNK * 16 * 1024 * 2 * 2
                             + (size_t)SCHUNK * 16 * 512 * 4;
    if (off < CHUNK_BYTES) off = (CHUNK_BYTES + 255) & ~(size_t)255;
    // Persistent:
    int* tk        = (int*)alloc((size_t)S * 1024 * 4);
    float* kvp     = (float*)alloc((size_t)S * 576 * 4);
    float* kv      = (float*)alloc((size_t)S * KV_LORA * 4);
    float* o2      = (float*)alloc((size_t)S * 2048 * 4);
    ushort_t* qah  = (ushort_t*)alloc((size_t)S * 16 * 576 * 2);
    ushort_t* qal  = (ushort_t*)alloc((size_t)S * 16 * 576 * 2);
    ushort_t* kvh  = (ushort_t*)alloc((size_t)S * 576 * 2);
    ushort_t* kvl  = (ushort_t*)alloc((size_t)S * 576 * 2);
    float* w1t     = (float*)alloc((size_t)16 * 512 * 128 * 4);
    // Chunk-phase aliases over region A:
    float* scb    = (float*)ws;
    ushort_t* pbh = (ushort_t*)(ws + (size_t)SCHUNK * 16 * 1024 * 4);
    ushort_t* pbl = pbh + (size_t)SCHUNK * 16 * 1024;
    float* o1c    = (float*)(ws + (size_t)SCHUNK * 16 * 1024 * 8);

    // ---- projections ----
    gemm3_bt<<<dim3(Q_LORA / 128, S / 128), 256, 0, stream>>>(x, q_a_proj, qr, S, Q_LORA, DIM, 1.f);
    rms_kernel<<<S, 256, 0, stream>>>(qr, qr, q_a_ln_w, Q_LORA, Q_LORA, Q_LORA);
    gemm3_bt<<<dim3(NH * QK_HD / 128, S / 128), 256, 0, stream>>>(qr, q_b_proj, q, S, NH * QK_HD, Q_LORA, 1.f);
    gemm3_bt<<<dim3(5, S / 128), 256, 0, stream>>>(x, kv_a_proj, kvp, S, 576, DIM, 1.f);
    rms_kernel<<<S, 256, 0, stream>>>(kvp, kv, kv_a_ln_w, KV_LORA, 576, KV_LORA);
    rope_inter_kernel<<<S * NH * 32 / 256, 256, 0, stream>>>(q, fcos, fsin, NH, QK_HD, QK_NOPE);
    rope_inter_kernel<<<S * 32 / 256, 256, 0, stream>>>(kvp, fcos, fsin, 1, 576, KV_LORA);
    // ---- indexer ----
    gemm3_bt<<<dim3(2048 / 128, S / 128), 256, 0, stream>>>(qr, idx_wq_b, iqf, S, 2048, Q_LORA, 1.f);
    rope_half_kernel<<<S * NH * 32 / 256, 256, 0, stream>>>(iqf, fcos, fsin, NH, 128);
    gemm3_bt<<<dim3(1, S / 128), 256, 0, stream>>>(x, idx_wk, ikf, S, 128, DIM, 1.f);
    ln_kernel<<<S, 128, 0, stream>>>(ikf, iknw, iknb);
    rope_half_kernel<<<S * 32 / 256, 256, 0, stream>>>(ikf, fcos, fsin, 1, 128);
    rotate_kernel<<<S * NH, 128, 0, stream>>>(iqf, iqr);
    rotate_kernel<<<S, 128, 0, stream>>>(ikf, ikr);
    gemm_nt<<<dim3(1, S / 64), 256, 0, stream>>>(x, idx_wp, iw, S, 16, DIM, 0.25f);
    wq_kernel<<<S * NH * 128 / 256, 256, 0, stream>>>(iw, iqr);
    iscore_mfma<<<dim3(16, 16), 256, 0, stream>>>(iqr, ikr, isc);
    topk_kernel<<<S, 256, 0, stream>>>(isc, tk);
    // ---- attention prep ----
    w1t_kernel<<<dim3(8, 2, 16), 256, 0, stream>>>(kv_b, w1t);
    kvsplit_kernel<<<S, 576, 0, stream>>>(kv, kvp, kvh, kvl);
    qabs_mfma<<<dim3(4, S / 128, 16), 256, 0, stream>>>(q, w1t, qah, qal);
    qpe_split<<<S * NH * 64 / 256, 256, 0, stream>>>(q, qah, qal);
    // ---- attention chunks ----
    for (int c = 0; c < 4; ++c) {
        int s0 = c * SCHUNK;
        attn_score_mfma<<<SCHUNK, 512, 0, stream>>>(qah, qal, kvh, kvl, tk, scb, s0);
        softmax_pb<<<SCHUNK * 16, 256, 0, stream>>>(scb, pbh, pbl);
        attn_pv_mfma<<<SCHUNK, 512, 0, stream>>>(pbh, pbl, kv, tk, o1c, s0);
        outproj_mfma<<<dim3(1, 4, 16), 256, 0, stream>>>(o1c, kv_b, o2, s0);
    }
    gemm3_bt<<<dim3(DIM / 128, S / 128), 256, 0, stream>>>(o2, o_proj, out, S, DIM, NH * V_HD, 1.f);
}

// Round 6
// 2373.988 us; speedup vs baseline: 3.8049x; 1.3285x over previous
//
#include <hip/hip_runtime.h>
#include <hip/hip_bf16.h>
#include <math.h>

#define S 2048
#define NH 16
#define DIM 2048
#define QK_NOPE 128
#define QK_ROPE 64
#define QK_HD 192
#define V_HD 128
#define Q_LORA 1536
#define KV_LORA 512
#define IDX_HD 128
#define SM_SCALE 0.07216878364870323f
#define SCHUNK 512
#define PADK 40
#define XPLD 2256   // packed x-proj output row stride: [qr 1536 | kvp 576 | ikf 128 | iw 16]
#define QLD 5120    // packed qr-proj output row stride: [q 3072 | iqf 2048]

typedef __hip_bfloat16 bf16;
typedef unsigned short ushort_t;
typedef __attribute__((ext_vector_type(8))) short short8;
typedef __attribute__((ext_vector_type(4))) float f32x4;

__device__ __forceinline__ f32x4 mfma_bf16(short8 a, short8 b, f32x4 c) {
    return __builtin_amdgcn_mfma_f32_16x16x32_bf16(a, b, c, 0, 0, 0);
}
__device__ __forceinline__ void async16(const void* g, void* l) {
    __builtin_amdgcn_global_load_lds((const __attribute__((address_space(1))) void*)g,
                                     (__attribute__((address_space(3))) void*)l, 16, 0, 0);
}
__device__ __forceinline__ unsigned short f2bf(float f) {  // RNE
    unsigned int u = __float_as_uint(f);
    return (unsigned short)((u + 0x7fff + ((u >> 16) & 1)) >> 16);
}
__device__ __forceinline__ float bf2f(unsigned short b) {
    return __uint_as_float(((unsigned int)b) << 16);
}

// ---------------- bf16x3 split MFMA GEMM: C[M,N] = A[M,K]f32 @ B[N,K]f32^T ----------------
__global__ __launch_bounds__(256) void gemm3_bt(const float* __restrict__ A, const float* __restrict__ B,
                                                float* __restrict__ C, int M, int N, int K) {
    __shared__ unsigned short Ah[128 * PADK], Al[128 * PADK], Bh[128 * PADK], Bl[128 * PADK];
    const int tid = threadIdx.x;
    const int bm = blockIdx.y * 128, bn = blockIdx.x * 128;
    const int w = tid >> 6, lane = tid & 63;
    const int wm = (w >> 1) * 64, wn = (w & 1) * 64;
    const int fr = lane & 15, fk = (lane >> 4) * 8;
    f32x4 acc[4][4];
    for (int i = 0; i < 4; ++i)
        for (int j = 0; j < 4; ++j) acc[i][j] = f32x4{0.f, 0.f, 0.f, 0.f};
    for (int k0 = 0; k0 < K; k0 += 32) {
        __syncthreads();
        for (int it = 0; it < 4; ++it) {
            int f = it * 256 + tid;
            int row = f >> 3, kc = (f & 7) * 4;
            float4 av = *(const float4*)(A + (size_t)(bm + row) * K + k0 + kc);
            float4 bv = make_float4(0.f, 0.f, 0.f, 0.f);
            if (bn + row < N) bv = *(const float4*)(B + (size_t)(bn + row) * K + k0 + kc);
            ushort4 ahi, alo, bhi, blo;
            ahi.x = f2bf(av.x); alo.x = f2bf(av.x - bf2f(ahi.x));
            ahi.y = f2bf(av.y); alo.y = f2bf(av.y - bf2f(ahi.y));
            ahi.z = f2bf(av.z); alo.z = f2bf(av.z - bf2f(ahi.z));
            ahi.w = f2bf(av.w); alo.w = f2bf(av.w - bf2f(ahi.w));
            bhi.x = f2bf(bv.x); blo.x = f2bf(bv.x - bf2f(bhi.x));
            bhi.y = f2bf(bv.y); blo.y = f2bf(bv.y - bf2f(bhi.y));
            bhi.z = f2bf(bv.z); blo.z = f2bf(bv.z - bf2f(bhi.z));
            bhi.w = f2bf(bv.w); blo.w = f2bf(bv.w - bf2f(bhi.w));
            *(ushort4*)&Ah[row * PADK + kc] = ahi;
            *(ushort4*)&Al[row * PADK + kc] = alo;
            *(ushort4*)&Bh[row * PADK + kc] = bhi;
            *(ushort4*)&Bl[row * PADK + kc] = blo;
        }
        __syncthreads();
        short8 ahf[4], alf[4], bhf[4], blf[4];
        for (int i = 0; i < 4; ++i) {
            int ro = (wm + i * 16 + fr) * PADK + fk;
            ahf[i] = *(const short8*)&Ah[ro];
            alf[i] = *(const short8*)&Al[ro];
        }
        for (int j = 0; j < 4; ++j) {
            int ro = (wn + j * 16 + fr) * PADK + fk;
            bhf[j] = *(const short8*)&Bh[ro];
            blf[j] = *(const short8*)&Bl[ro];
        }
        for (int i = 0; i < 4; ++i)
            for (int j = 0; j < 4; ++j) {
                acc[i][j] = mfma_bf16(ahf[i], bhf[j], acc[i][j]);
                acc[i][j] = mfma_bf16(ahf[i], blf[j], acc[i][j]);
                acc[i][j] = mfma_bf16(alf[i], bhf[j], acc[i][j]);
            }
    }
    const int cr = (lane >> 4) * 4, cc = lane & 15;
    for (int i = 0; i < 4; ++i)
        for (int j = 0; j < 4; ++j) {
            int row = bm + wm + i * 16 + cr;
            int col = bn + wn + j * 16 + cc;
            if (col < N)
                for (int r = 0; r < 4; ++r)
                    C[(size_t)(row + r) * N + col] = acc[i][j][r];
        }
}

// ---------------- RMSNorm (strided in/out) ----------------
__global__ __launch_bounds__(256) void rms_kernel(const float* __restrict__ in, float* __restrict__ out,
                                                  const float* __restrict__ w, int C, int ldin, int ldout) {
    const int row = blockIdx.x;
    const float* xr = in + (size_t)row * ldin;
    float* yr = out + (size_t)row * ldout;
    float ss = 0.f;
    for (int c = threadIdx.x; c < C; c += 256) { float v = xr[c]; ss += v * v; }
    for (int o = 32; o; o >>= 1) ss += __shfl_down(ss, o, 64);
    __shared__ float red[4];
    const int wave = threadIdx.x >> 6, lane = threadIdx.x & 63;
    if (lane == 0) red[wave] = ss;
    __syncthreads();
    const float tot = red[0] + red[1] + red[2] + red[3];
    const float scale = rsqrtf(tot / (float)C + 1e-6f);
    for (int c = threadIdx.x; c < C; c += 256) yr[c] = w[c] * (xr[c] * scale);
}

// ---------------- LayerNorm row length 128 (strided, in place) ----------------
__global__ __launch_bounds__(128) void ln_kernel(float* __restrict__ x, const float* __restrict__ w,
                                                 const float* __restrict__ b, int ld) {
    const int row = blockIdx.x;
    float* xr = x + (size_t)row * ld;
    const int tid = threadIdx.x;
    float v = xr[tid];
    float sm = v;
    for (int o = 32; o; o >>= 1) sm += __shfl_down(sm, o, 64);
    __shared__ float red[2];
    if ((tid & 63) == 0) red[tid >> 6] = sm;
    __syncthreads();
    const float mu = (red[0] + red[1]) * (1.f / 128.f);
    __syncthreads();
    float d = v - mu;
    float sv = d * d;
    for (int o = 32; o; o >>= 1) sv += __shfl_down(sv, o, 64);
    if ((tid & 63) == 0) red[tid >> 6] = sv;
    __syncthreads();
    const float var = (red[0] + red[1]) * (1.f / 128.f);
    const float rs = rsqrtf(var + 1e-6f);
    xr[tid] = (v - mu) * rs * w[tid] + b[tid];
}

// ---------------- RoPE interleaved: p = X + s*ld + h*hs + off ----------------
__global__ __launch_bounds__(256) void rope_inter_kernel(float* __restrict__ X, const float* __restrict__ ct,
                                                         const float* __restrict__ st, int H, int hs, int off,
                                                         int ld) {
    int idx = blockIdx.x * 256 + threadIdx.x;
    int k = idx & 31;
    int h = (idx >> 5) % H;
    int s = idx / (32 * H);
    if (s >= S) return;
    float c = ct[s * 32 + k], sn = st[s * 32 + k];
    float* p = X + (size_t)s * ld + h * hs + off;
    float x1 = p[2 * k], x2 = p[2 * k + 1];
    p[2 * k]     = x1 * c - x2 * sn;
    p[2 * k + 1] = x1 * sn + x2 * c;
}

// ---------------- RoPE half: p = X + s*ld + h*hs ----------------
__global__ __launch_bounds__(256) void rope_half_kernel(float* __restrict__ X, const float* __restrict__ ct,
                                                        const float* __restrict__ st, int H, int hs, int ld) {
    int idx = blockIdx.x * 256 + threadIdx.x;
    int k = idx & 31;
    int h = (idx >> 5) % H;
    int s = idx / (32 * H);
    if (s >= S) return;
    float c = ct[s * 32 + k], sn = st[s * 32 + k];
    float* p = X + (size_t)s * ld + h * hs;
    float x1 = p[k], x2 = p[32 + k];
    p[k]      = x1 * c - x2 * sn;
    p[32 + k] = x1 * sn + x2 * c;
}

// ---------------- Hadamard rotate: in strided (s*lds + h*128), out packed r*128 ----------------
__global__ __launch_bounds__(128) void rotate_kernel(const float* __restrict__ in, int lds, int H,
                                                     bf16* __restrict__ out) {
    __shared__ float xs[128];
    const int r = blockIdx.x, j = threadIdx.x;
    const int s = r / H, h = r - s * H;
    float v = in[(size_t)s * lds + h * 128 + j];
    xs[j] = __bfloat162float(__float2bfloat16(v));
    __syncthreads();
    float acc = 0.f;
    for (int d = 0; d < 128; ++d) {
        float xv = xs[d];
        acc += (__popc(d & j) & 1) ? -xv : xv;
    }
    float t = __bfloat162float(__float2bfloat16(acc)) * 0.08838834764831845f;
    out[(size_t)r * 128 + j] = __float2bfloat16(t);
}

// ---------------- wq scale: iw read from strided xp slice; 0.25 folded here ----------------
__global__ __launch_bounds__(256) void wq_kernel(const float* __restrict__ iwb, bf16* __restrict__ iqr) {
    int idx = blockIdx.x * 256 + threadIdx.x;
    int s = idx >> 11, h = (idx >> 7) & 15;
    float a = 0.25f * iwb[(size_t)s * XPLD + h];
    float v = __bfloat162float(iqr[idx]);
    float t = (a * v) * 0.08838834764831845f;
    iqr[idx] = __float2bfloat16(t);
}

// ---------------- index score via bf16 MFMA ----------------
__global__ __launch_bounds__(256) void iscore_mfma(const bf16* __restrict__ wq, const bf16* __restrict__ ik,
                                                   float* __restrict__ out) {
    if (blockIdx.x > blockIdx.y) return;
    __shared__ unsigned short As[128 * 32], Bs[128 * 32];
    const int bs = blockIdx.y * 128, bt = blockIdx.x * 128;
    const int tid = threadIdx.x, w = tid >> 6, lane = tid & 63;
    const int wm = (w >> 1) * 64, wn = (w & 1) * 64;
    const int fr = lane & 15, fk = (lane >> 4) * 8;
    const int srow = lane >> 2, skc = (lane & 3) * 8;
    f32x4 sum[4][4];
    for (int i = 0; i < 4; ++i)
        for (int j = 0; j < 4; ++j) sum[i][j] = f32x4{0.f, 0.f, 0.f, 0.f};
    for (int h = 0; h < 16; ++h) {
        f32x4 acc[4][4];
        for (int i = 0; i < 4; ++i)
            for (int j = 0; j < 4; ++j) acc[i][j] = f32x4{0.f, 0.f, 0.f, 0.f};
        for (int k0 = 0; k0 < 128; k0 += 32) {
            __syncthreads();
            for (int i = 0; i < 2; ++i) {
                int seg = i * 4 + w;
                async16(wq + (size_t)(bs + seg * 16 + srow) * 2048 + h * 128 + k0 + skc, &As[seg * 512]);
                async16(ik + (size_t)(bt + seg * 16 + srow) * 128 + k0 + skc, &Bs[seg * 512]);
            }
            __syncthreads();
            short8 af[4], bff[4];
            for (int i = 0; i < 4; ++i) af[i]  = *(const short8*)&As[(wm + i * 16 + fr) * 32 + fk];
            for (int j = 0; j < 4; ++j) bff[j] = *(const short8*)&Bs[(wn + j * 16 + fr) * 32 + fk];
            for (int i = 0; i < 4; ++i)
                for (int j = 0; j < 4; ++j)
                    acc[i][j] = mfma_bf16(af[i], bff[j], acc[i][j]);
        }
        for (int i = 0; i < 4; ++i)
            for (int j = 0; j < 4; ++j)
                for (int r = 0; r < 4; ++r)
                    sum[i][j][r] += fmaxf(acc[i][j][r], 0.f);
    }
    const int cr = (lane >> 4) * 4, cc = lane & 15;
    for (int i = 0; i < 4; ++i)
        for (int j = 0; j < 4; ++j)
            for (int r = 0; r < 4; ++r)
                out[(size_t)(bs + wm + i * 16 + cr + r) * 2048 + bt + wn + j * 16 + cc] = sum[i][j][r];
}

// ---------------- top-k ----------------
__global__ __launch_bounds__(256) void topk_kernel(const float* __restrict__ isc, int* __restrict__ tk) {
    __shared__ unsigned long long keys[2048];
    const int s = blockIdx.x;
    const float* row = isc + (size_t)s * 2048;
    for (int t = threadIdx.x; t < 2048; t += 256) {
        unsigned long long kk = 0ull;
        if (t <= s) {
            unsigned int vb = __float_as_uint(row[t]);
            kk = ((unsigned long long)vb << 32) | (unsigned int)(2048 - t);
        }
        keys[t] = kk;
    }
    __syncthreads();
    for (int k = 2; k <= 2048; k <<= 1) {
        for (int j = k >> 1; j > 0; j >>= 1) {
            for (int t = threadIdx.x; t < 2048; t += 256) {
                int l = t ^ j;
                if (l > t) {
                    bool up = ((t & k) == 0);
                    unsigned long long a = keys[t], b = keys[l];
                    bool sw = up ? (a < b) : (a > b);
                    if (sw) { keys[t] = b; keys[l] = a; }
                }
            }
            __syncthreads();
        }
    }
    const int cnt = min(1024, s + 1);
    for (int i = threadIdx.x; i < 1024; i += 256) {
        int t = (i < cnt) ? (2048 - (int)(keys[i] & 0xFFFFFFFFull)) : -1;
        tk[(size_t)s * 1024 + i] = t;
    }
}

// ---------------- transpose kv_b head-1 part ----------------
__global__ __launch_bounds__(256) void w1t_kernel(const float* __restrict__ kv_b, float* __restrict__ w1t) {
    __shared__ float ts[64][65];
    const int cb = blockIdx.x * 64, db = blockIdx.y * 64, h = blockIdx.z;
    const int t = threadIdx.x;
    for (int it = 0; it < 16; ++it) {
        int idx = it * 256 + t;
        int rr = idx >> 6, cc = idx & 63;
        ts[rr][cc] = kv_b[(size_t)(h * 256 + db + rr) * 512 + cb + cc];
    }
    __syncthreads();
    for (int it = 0; it < 16; ++it) {
        int idx = it * 256 + t;
        int rr = idx >> 6, cc = idx & 63;
        w1t[(size_t)h * 65536 + (size_t)(cb + rr) * 128 + db + cc] = ts[cc][rr];
    }
}

// ---------------- kv split: cols<512 from kv, cols 512..575 from roped k_pe slice of xp ----------------
__global__ __launch_bounds__(576) void kvsplit_kernel(const float* __restrict__ kv, const float* __restrict__ kpe,
                                                      ushort_t* __restrict__ kvh, ushort_t* __restrict__ kvl) {
    const int t = blockIdx.x, c = threadIdx.x;
    float v = (c < 512) ? kv[(size_t)t * 512 + c] : kpe[(size_t)t * XPLD + c];
    unsigned short hi = f2bf(v);
    kvh[(size_t)t * 576 + c] = hi;
    kvl[(size_t)t * 576 + c] = f2bf(v - bf2f(hi));
}

// ---------------- qabs via bf16x3 MFMA (q strided from packed qib) ----------------
__global__ __launch_bounds__(256) void qabs_mfma(const float* __restrict__ q, const float* __restrict__ w1t,
                                                 ushort_t* __restrict__ qah, ushort_t* __restrict__ qal) {
    __shared__ unsigned short Ah[128 * PADK], Al[128 * PADK], Bh[128 * PADK], Bl[128 * PADK];
    const int tid = threadIdx.x;
    const int bn = blockIdx.x * 128, bm = blockIdx.y * 128, h = blockIdx.z;
    const int w = tid >> 6, lane = tid & 63;
    const int wm = (w >> 1) * 64, wn = (w & 1) * 64;
    const int fr = lane & 15, fk = (lane >> 4) * 8;
    f32x4 acc[4][4];
    for (int i = 0; i < 4; ++i)
        for (int j = 0; j < 4; ++j) acc[i][j] = f32x4{0.f, 0.f, 0.f, 0.f};
    for (int k0 = 0; k0 < 128; k0 += 32) {
        __syncthreads();
        for (int it = 0; it < 4; ++it) {
            int f = it * 256 + tid;
            int row = f >> 3, kc = (f & 7) * 4;
            float4 av = *(const float4*)(q + (size_t)(bm + row) * QLD + h * QK_HD + k0 + kc);
            float4 bv = *(const float4*)(w1t + (size_t)h * 65536 + (size_t)(bn + row) * 128 + k0 + kc);
            ushort4 ahi, alo, bhi, blo;
            ahi.x = f2bf(av.x); alo.x = f2bf(av.x - bf2f(ahi.x));
            ahi.y = f2bf(av.y); alo.y = f2bf(av.y - bf2f(ahi.y));
            ahi.z = f2bf(av.z); alo.z = f2bf(av.z - bf2f(ahi.z));
            ahi.w = f2bf(av.w); alo.w = f2bf(av.w - bf2f(ahi.w));
            bhi.x = f2bf(bv.x); blo.x = f2bf(bv.x - bf2f(bhi.x));
            bhi.y = f2bf(bv.y); blo.y = f2bf(bv.y - bf2f(bhi.y));
            bhi.z = f2bf(bv.z); blo.z = f2bf(bv.z - bf2f(bhi.z));
            bhi.w = f2bf(bv.w); blo.w = f2bf(bv.w - bf2f(bhi.w));
            *(ushort4*)&Ah[row * PADK + kc] = ahi;
            *(ushort4*)&Al[row * PADK + kc] = alo;
            *(ushort4*)&Bh[row * PADK + kc] = bhi;
            *(ushort4*)&Bl[row * PADK + kc] = blo;
        }
        __syncthreads();
        short8 ahf[4], alf[4], bhf[4], blf[4];
        for (int i = 0; i < 4; ++i) {
            int ro = (wm + i * 16 + fr) * PADK + fk;
            ahf[i] = *(const short8*)&Ah[ro];
            alf[i] = *(const short8*)&Al[ro];
        }
        for (int j = 0; j < 4; ++j) {
            int ro = (wn + j * 16 + fr) * PADK + fk;
            bhf[j] = *(const short8*)&Bh[ro];
            blf[j] = *(const short8*)&Bl[ro];
        }
        for (int i = 0; i < 4; ++i)
            for (int j = 0; j < 4; ++j) {
                acc[i][j] = mfma_bf16(ahf[i], bhf[j], acc[i][j]);
                acc[i][j] = mfma_bf16(ahf[i], blf[j], acc[i][j]);
                acc[i][j] = mfma_bf16(alf[i], bhf[j], acc[i][j]);
            }
    }
    const int cr = (lane >> 4) * 4, cc = lane & 15;
    for (int i = 0; i < 4; ++i)
        for (int j = 0; j < 4; ++j)
            for (int r = 0; r < 4; ++r) {
                int srow = bm + wm + i * 16 + cr + r;
                int col = bn + wn + j * 16 + cc;
                float f = acc[i][j][r] * SM_SCALE;
                size_t addr = ((size_t)srow * 16 + h) * 576 + col;
                unsigned short hi = f2bf(f);
                qah[addr] = hi;
                qal[addr] = f2bf(f - bf2f(hi));
            }
}

// ---------------- qpe split (q strided from packed qib) ----------------
__global__ __launch_bounds__(256) void qpe_split(const float* __restrict__ q, ushort_t* __restrict__ qah,
                                                 ushort_t* __restrict__ qal) {
    int idx = blockIdx.x * 256 + threadIdx.x;
    int r = idx & 63, h = (idx >> 6) & 15, s = idx >> 10;
    float f = q[(size_t)s * QLD + h * QK_HD + 128 + r] * SM_SCALE;
    size_t addr = ((size_t)s * 16 + h) * 576 + 512 + r;
    unsigned short hi = f2bf(f);
    qah[addr] = hi;
    qal[addr] = f2bf(f - bf2f(hi));
}

// ---------------- attn_score via MFMA bf16x3 ----------------
__global__ __launch_bounds__(512) void attn_score_mfma(const ushort_t* __restrict__ qah,
                                                       const ushort_t* __restrict__ qal,
                                                       const ushort_t* __restrict__ kvh,
                                                       const ushort_t* __restrict__ kvl,
                                                       const int* __restrict__ tk,
                                                       float* __restrict__ scb, int s0) {
    const int sl = blockIdx.x, s = s0 + sl;
    const int tid = threadIdx.x, w = tid >> 6, lane = tid & 63;
    __shared__ int tks[1024];
    __shared__ unsigned short kh[256 * 40], kl[256 * 40];
    const int cnt = min(1024, s + 1);
    for (int j = tid; j < 1024; j += 512) {
        int t = tk[(size_t)s * 1024 + j];
        tks[j] = t < 0 ? 0 : t;
    }
    __syncthreads();
    const int fr = lane & 15, fko = (lane >> 4) * 8;
    const size_t abase = ((size_t)s * 16 + fr) * 576 + fko;
    const int srow = tid >> 1, sseg = tid & 1;
    for (int pass = 0; pass < 4; ++pass) {
        f32x4 acc0 = {0.f, 0.f, 0.f, 0.f}, acc1 = {0.f, 0.f, 0.f, 0.f};
        for (int ch = 0; ch < 18; ++ch) {
            const int k0 = ch * 32;
            __syncthreads();
            {
                int t = tks[pass * 256 + srow];
                const ushort_t* gh = kvh + (size_t)t * 576 + k0 + sseg * 16;
                const ushort_t* gl = kvl + (size_t)t * 576 + k0 + sseg * 16;
                *(int4*)&kh[srow * 40 + sseg * 16]     = *(const int4*)gh;
                *(int4*)&kh[srow * 40 + sseg * 16 + 8] = *(const int4*)(gh + 8);
                *(int4*)&kl[srow * 40 + sseg * 16]     = *(const int4*)gl;
                *(int4*)&kl[srow * 40 + sseg * 16 + 8] = *(const int4*)(gl + 8);
            }
            __syncthreads();
            short8 ah = *(const short8*)(qah + abase + k0);
            short8 al = *(const short8*)(qal + abase + k0);
            {
                int ro = (w * 32 + fr) * 40 + fko;
                short8 bh = *(const short8*)&kh[ro];
                short8 bl = *(const short8*)&kl[ro];
                acc0 = mfma_bf16(ah, bh, acc0);
                acc0 = mfma_bf16(ah, bl, acc0);
                acc0 = mfma_bf16(al, bh, acc0);
            }
            {
                int ro = (w * 32 + 16 + fr) * 40 + fko;
                short8 bh = *(const short8*)&kh[ro];
                short8 bl = *(const short8*)&kl[ro];
                acc1 = mfma_bf16(ah, bh, acc1);
                acc1 = mfma_bf16(ah, bl, acc1);
                acc1 = mfma_bf16(al, bh, acc1);
            }
        }
        const int cr = (lane >> 4) * 4, cc = lane & 15;
        for (int r = 0; r < 4; ++r) {
            int head = cr + r;
            int key0 = pass * 256 + w * 32 + cc;
            int key1 = key0 + 16;
            scb[((size_t)sl * 16 + head) * 1024 + key0] = (key0 < cnt) ? acc0[r] : -1e30f;
            scb[((size_t)sl * 16 + head) * 1024 + key1] = (key1 < cnt) ? acc1[r] : -1e30f;
        }
    }
}

// ---------------- softmax -> p as bf16 hi/lo ----------------
__global__ __launch_bounds__(256) void softmax_pb(const float* __restrict__ scb,
                                                  ushort_t* __restrict__ pbh, ushort_t* __restrict__ pbl) {
    const size_t row = blockIdx.x;
    const float* src = scb + row * 1024;
    const int tid = threadIdx.x, wave = tid >> 6, lane = tid & 63;
    __shared__ float red[4];
    float v[4];
    float m = -INFINITY;
    for (int i = 0; i < 4; ++i) { v[i] = src[tid + 256 * i]; m = fmaxf(m, v[i]); }
    for (int o = 32; o; o >>= 1) m = fmaxf(m, __shfl_down(m, o, 64));
    if (lane == 0) red[wave] = m;
    __syncthreads();
    m = fmaxf(fmaxf(red[0], red[1]), fmaxf(red[2], red[3]));
    __syncthreads();
    float e[4], l = 0.f;
    for (int i = 0; i < 4; ++i) { e[i] = __expf(v[i] - m); l += e[i]; }
    for (int o = 32; o; o >>= 1) l += __shfl_down(l, o, 64);
    if (lane == 0) red[wave] = l;
    __syncthreads();
    const float il = 1.f / (red[0] + red[1] + red[2] + red[3]);
    for (int i = 0; i < 4; ++i) {
        float p = e[i] * il;
        unsigned short hi = f2bf(p);
        pbh[row * 1024 + tid + 256 * i] = hi;
        pbl[row * 1024 + tid + 256 * i] = f2bf(p - bf2f(hi));
    }
}

// ---------------- attn_pv via MFMA bf16x3 ----------------
__global__ __launch_bounds__(512) void attn_pv_mfma(const ushort_t* __restrict__ pbh,
                                                    const ushort_t* __restrict__ pbl,
                                                    const float* __restrict__ kv,
                                                    const int* __restrict__ tk,
                                                    float* __restrict__ o1, int s0) {
    const int sl = blockIdx.x, s = s0 + sl;
    const int tid = threadIdx.x, w = tid >> 6, lane = tid & 63;
    __shared__ int tks[1024];
    __shared__ float vt[32 * 514];
    for (int j = tid; j < 1024; j += 512) {
        int t = tk[(size_t)s * 1024 + j];
        tks[j] = t < 0 ? 0 : t;
    }
    const int fr = lane & 15, fko = (lane >> 4) * 8;
    f32x4 acc[4];
    for (int i = 0; i < 4; ++i) acc[i] = f32x4{0.f, 0.f, 0.f, 0.f};
    const size_t pbase = ((size_t)sl * 16 + fr) * 1024 + fko;
    for (int kc = 0; kc < 32; ++kc) {
        __syncthreads();
        for (int it = 0; it < 8; ++it) {
            int task = it * 512 + tid;
            int rrow = task >> 7, c4 = task & 127;
            *(float4*)&vt[rrow * 514 + c4 * 4] =
                *(const float4*)(kv + (size_t)tks[kc * 32 + rrow] * 512 + c4 * 4);
        }
        __syncthreads();
        short8 ph = *(const short8*)(pbh + pbase + kc * 32);
        short8 pl = *(const short8*)(pbl + pbase + kc * 32);
        for (int sub = 0; sub < 4; ++sub) {
            int cbase = w * 64 + sub * 16 + fr;
            short8 bh, bl;
            for (int jj = 0; jj < 8; ++jj) {
                float vv = vt[(fko + jj) * 514 + cbase];
                unsigned short hv = f2bf(vv);
                bh[jj] = (short)hv;
                bl[jj] = (short)f2bf(vv - bf2f(hv));
            }
            acc[sub] = mfma_bf16(ph, bh, acc[sub]);
            acc[sub] = mfma_bf16(pl, bh, acc[sub]);
            acc[sub] = mfma_bf16(ph, bl, acc[sub]);
        }
    }
    const int cr = (lane >> 4) * 4, cc = lane & 15;
    for (int sub = 0; sub < 4; ++sub)
        for (int r = 0; r < 4; ++r) {
            int head = cr + r, c = w * 64 + sub * 16 + cc;
            o1[((size_t)sl * 16 + head) * 512 + c] = acc[sub][r];
        }
}

// ---------------- outproj via bf16x3 MFMA ----------------
__global__ __launch_bounds__(256) void outproj_mfma(const float* __restrict__ o1, const float* __restrict__ kv_b,
                                                    float* __restrict__ o2, int s0) {
    __shared__ unsigned short Ah[128 * PADK], Al[128 * PADK], Bh[128 * PADK], Bl[128 * PADK];
    const int tid = threadIdx.x;
    const int bm = blockIdx.y * 128, h = blockIdx.z;
    const int w = tid >> 6, lane = tid & 63;
    const int wm = (w >> 1) * 64, wn = (w & 1) * 64;
    const int fr = lane & 15, fk = (lane >> 4) * 8;
    f32x4 acc[4][4];
    for (int i = 0; i < 4; ++i)
        for (int j = 0; j < 4; ++j) acc[i][j] = f32x4{0.f, 0.f, 0.f, 0.f};
    for (int k0 = 0; k0 < 512; k0 += 32) {
        __syncthreads();
        for (int it = 0; it < 4; ++it) {
            int f = it * 256 + tid;
            int row = f >> 3, kc = (f & 7) * 4;
            float4 av = *(const float4*)(o1 + ((size_t)(bm + row) * 16 + h) * 512 + k0 + kc);
            float4 bv = *(const float4*)(kv_b + (size_t)(h * 256 + 128 + row) * 512 + k0 + kc);
            ushort4 ahi, alo, bhi, blo;
            ahi.x = f2bf(av.x); alo.x = f2bf(av.x - bf2f(ahi.x));
            ahi.y = f2bf(av.y); alo.y = f2bf(av.y - bf2f(ahi.y));
            ahi.z = f2bf(av.z); alo.z = f2bf(av.z - bf2f(ahi.z));
            ahi.w = f2bf(av.w); alo.w = f2bf(av.w - bf2f(ahi.w));
            bhi.x = f2bf(bv.x); blo.x = f2bf(bv.x - bf2f(bhi.x));
            bhi.y = f2bf(bv.y); blo.y = f2bf(bv.y - bf2f(bhi.y));
            bhi.z = f2bf(bv.z); blo.z = f2bf(bv.z - bf2f(bhi.z));
            bhi.w = f2bf(bv.w); blo.w = f2bf(bv.w - bf2f(bhi.w));
            *(ushort4*)&Ah[row * PADK + kc] = ahi;
            *(ushort4*)&Al[row * PADK + kc] = alo;
            *(ushort4*)&Bh[row * PADK + kc] = bhi;
            *(ushort4*)&Bl[row * PADK + kc] = blo;
        }
        __syncthreads();
        short8 ahf[4], alf[4], bhf[4], blf[4];
        for (int i = 0; i < 4; ++i) {
            int ro = (wm + i * 16 + fr) * PADK + fk;
            ahf[i] = *(const short8*)&Ah[ro];
            alf[i] = *(const short8*)&Al[ro];
        }
        for (int j = 0; j < 4; ++j) {
            int ro = (wn + j * 16 + fr) * PADK + fk;
            bhf[j] = *(const short8*)&Bh[ro];
            blf[j] = *(const short8*)&Bl[ro];
        }
        for (int i = 0; i < 4; ++i)
            for (int j = 0; j < 4; ++j) {
                acc[i][j] = mfma_bf16(ahf[i], bhf[j], acc[i][j]);
                acc[i][j] = mfma_bf16(ahf[i], blf[j], acc[i][j]);
                acc[i][j] = mfma_bf16(alf[i], bhf[j], acc[i][j]);
            }
    }
    const int cr = (lane >> 4) * 4, cc = lane & 15;
    for (int i = 0; i < 4; ++i)
        for (int j = 0; j < 4; ++j)
            for (int r = 0; r < 4; ++r) {
                int srow = s0 + bm + wm + i * 16 + cr + r;
                int col = wn + j * 16 + cc;
                o2[(size_t)srow * 2048 + h * 128 + col] = acc[i][j][r];
            }
}

extern "C" void kernel_launch(void* const* d_in, const int* in_sizes, int n_in,
                              void* d_out, int out_size, void* d_ws, size_t ws_size,
                              hipStream_t stream) {
    const float* x         = (const float*)d_in[0];
    const float* fcos      = (const float*)d_in[2];
    const float* fsin      = (const float*)d_in[3];
    const float* q_a_proj  = (const float*)d_in[5];
    const float* q_a_ln_w  = (const float*)d_in[6];
    const float* q_b_proj  = (const float*)d_in[7];
    const float* kv_a_proj = (const float*)d_in[8];
    const float* kv_a_ln_w = (const float*)d_in[9];
    const float* kv_b      = (const float*)d_in[10];
    const float* o_proj    = (const float*)d_in[11];
    const float* idx_wq_b  = (const float*)d_in[12];
    const float* idx_wk    = (const float*)d_in[13];
    const float* iknw      = (const float*)d_in[14];
    const float* iknb      = (const float*)d_in[15];
    const float* idx_wp    = (const float*)d_in[16];
    float* out = (float*)d_out;

    char* ws = (char*)d_ws;
    size_t off = 0;
    auto alloc = [&](size_t bytes) {
        char* p = ws + off;
        off += (bytes + 255) & ~(size_t)255;
        return p;
    };
    // ---- Region A (dead by attention-chunk phase; overlaid by scb/pbh/pbl/o1c) ----
    float* xp  = (float*)alloc((size_t)S * XPLD * 4);   // 18.5 MB: [qr-in 1536 | kvp 576 | ikf 128 | iw 16]
    float* qr  = (float*)alloc((size_t)S * Q_LORA * 4); // 12.6 MB (rms'd q lora)
    float* qib = (float*)alloc((size_t)S * QLD * 4);    // 41.9 MB: [q 3072 | iqf 2048]
    char* RAt  = alloc(31457280);                       // 31.5 MB: wq2 / (isc+iqr+ikr) / w1t overlays
    float* isc = (float*)RAt;                           // 16.8 MB
    bf16* iqr  = (bf16*)(RAt + 16777216);               // 8.4 MB
    bf16* ikr  = (bf16*)(RAt + 16777216 + 8388608);     // 0.5 MB
    float* wq2 = (float*)RAt;                           // 31.5 MB (dead before isc written)
    float* w1t = (float*)RAt;                           // 4.2 MB (written after topk reads isc)
    float* wpack = qib;                                 // 18.5 MB (dead before qib written)
    // pad region A to cover chunk scratch (scb 32MiB + pbh 16 + pbl 16 + o1c 16 = 80 MiB)
    const size_t CHUNK_BYTES = (size_t)SCHUNK * 16 * 1024 * 4 + (size_t)SCHUNK * 16 * 1024 * 2 * 2
                             + (size_t)SCHUNK * 16 * 512 * 4;
    if (off < CHUNK_BYTES) off = (CHUNK_BYTES + 255) & ~(size_t)255;
    // ---- Persistent ----
    int* tk        = (int*)alloc((size_t)S * 1024 * 4);
    float* kv      = (float*)alloc((size_t)S * KV_LORA * 4);
    float* o2      = (float*)alloc((size_t)S * 2048 * 4);
    ushort_t* qah  = (ushort_t*)alloc((size_t)S * 16 * 576 * 2);
    ushort_t* qal  = (ushort_t*)alloc((size_t)S * 16 * 576 * 2);
    ushort_t* kvh  = (ushort_t*)alloc((size_t)S * 576 * 2);
    ushort_t* kvl  = (ushort_t*)alloc((size_t)S * 576 * 2);
    // ---- Chunk-phase aliases over region A ----
    float* scb    = (float*)ws;
    ushort_t* pbh = (ushort_t*)(ws + (size_t)SCHUNK * 16 * 1024 * 4);
    ushort_t* pbl = pbh + (size_t)SCHUNK * 16 * 1024;
    float* o1c    = (float*)(ws + (size_t)SCHUNK * 16 * 1024 * 8);

    // ---- fused x-projection: wpack = [q_a | kv_a | idx_wk | idx_wp], one GEMM N=2256 ----
    hipMemcpyAsync(wpack,                      q_a_proj,  (size_t)Q_LORA * DIM * 4, hipMemcpyDeviceToDevice, stream);
    hipMemcpyAsync(wpack + (size_t)1536 * DIM, kv_a_proj, (size_t)576 * DIM * 4,    hipMemcpyDeviceToDevice, stream);
    hipMemcpyAsync(wpack + (size_t)2112 * DIM, idx_wk,    (size_t)128 * DIM * 4,    hipMemcpyDeviceToDevice, stream);
    hipMemcpyAsync(wpack + (size_t)2240 * DIM, idx_wp,    (size_t)16 * DIM * 4,     hipMemcpyDeviceToDevice, stream);
    gemm3_bt<<<dim3((XPLD + 127) / 128, S / 128), 256, 0, stream>>>(x, wpack, xp, S, XPLD, DIM);
    rms_kernel<<<S, 256, 0, stream>>>(xp, qr, q_a_ln_w, Q_LORA, XPLD, Q_LORA);
    rms_kernel<<<S, 256, 0, stream>>>(xp + 1536, kv, kv_a_ln_w, KV_LORA, XPLD, KV_LORA);
    // ---- fused qr-projection: wq2 = [q_b | idx_wq_b], one GEMM N=5120 ----
    hipMemcpyAsync(wq2,                          q_b_proj, (size_t)3072 * Q_LORA * 4, hipMemcpyDeviceToDevice, stream);
    hipMemcpyAsync(wq2 + (size_t)3072 * Q_LORA, idx_wq_b,  (size_t)2048 * Q_LORA * 4, hipMemcpyDeviceToDevice, stream);
    gemm3_bt<<<dim3(QLD / 128, S / 128), 256, 0, stream>>>(qr, wq2, qib, S, QLD, Q_LORA);
    // ---- rope ----
    rope_inter_kernel<<<S * NH * 32 / 256, 256, 0, stream>>>(qib, fcos, fsin, NH, QK_HD, QK_NOPE, QLD);
    rope_inter_kernel<<<S * 32 / 256, 256, 0, stream>>>(xp + 1536, fcos, fsin, 1, 0, KV_LORA, XPLD);
    rope_half_kernel<<<S * NH * 32 / 256, 256, 0, stream>>>(qib + 3072, fcos, fsin, NH, 128, QLD);
    // ---- indexer ----
    ln_kernel<<<S, 128, 0, stream>>>(xp + 2112, iknw, iknb, XPLD);
    rope_half_kernel<<<S * 32 / 256, 256, 0, stream>>>(xp + 2112, fcos, fsin, 1, 0, XPLD);
    rotate_kernel<<<S * NH, 128, 0, stream>>>(qib + 3072, QLD, NH, iqr);
    rotate_kernel<<<S, 128, 0, stream>>>(xp + 2112, XPLD, 1, ikr);
    wq_kernel<<<S * NH * 128 / 256, 256, 0, stream>>>(xp + 2240, iqr);
    iscore_mfma<<<dim3(16, 16), 256, 0, stream>>>(iqr, ikr, isc);
    topk_kernel<<<S, 256, 0, stream>>>(isc, tk);
    // ---- attention prep ----
    w1t_kernel<<<dim3(8, 2, 16), 256, 0, stream>>>(kv_b, w1t);
    kvsplit_kernel<<<S, 576, 0, stream>>>(kv, xp + 1536, kvh, kvl);
    qabs_mfma<<<dim3(4, S / 128, 16), 256, 0, stream>>>(qib, w1t, qah, qal);
    qpe_split<<<S * NH * 64 / 256, 256, 0, stream>>>(qib, qah, qal);
    // ---- attention chunks ----
    for (int c = 0; c < 4; ++c) {
        int s0 = c * SCHUNK;
        attn_score_mfma<<<SCHUNK, 512, 0, stream>>>(qah, qal, kvh, kvl, tk, scb, s0);
        softmax_pb<<<SCHUNK * 16, 256, 0, stream>>>(scb, pbh, pbl);
        attn_pv_mfma<<<SCHUNK, 512, 0, stream>>>(pbh, pbl, kv, tk, o1c, s0);
        outproj_mfma<<<dim3(1, 4, 16), 256, 0, stream>>>(o1c, kv_b, o2, s0);
    }
    gemm3_bt<<<dim3(DIM / 128, S / 128), 256, 0, stream>>>(o2, o_proj, out, S, DIM, NH * V_HD);
}